// Round 1
// baseline (1081.984 us; speedup 1.0000x reference)
//
#include <hip/hip_runtime.h>

namespace {
constexpr int H = 200, W = 200, HW = H * W;
constexpr int Bz = 4;
constexpr int PW = 208, PH = 202, PPLANE = PW * PH; // conv1x1 pad geometry (halo 1)
constexpr int EPW = 208, EPH = 208, EPL = EPW * EPH; // e-pad geometry (halo 4)
}

typedef __attribute__((ext_vector_type(8))) short bf16x8;
typedef __attribute__((ext_vector_type(4))) float f32x4;

__device__ inline ushort f2bf(float f) {
  unsigned u = __float_as_uint(f);
  u += 0x7fffu + ((u >> 16) & 1u);
  return (ushort)(u >> 16);
}

// ---------------- zero fill ----------------
__global__ __launch_bounds__(256) void zero_k(uint4* __restrict__ p, int n) {
  int i = blockIdx.x * 256 + threadIdx.x;
  if (i < n) p[i] = uint4{0u, 0u, 0u, 0u};
}

// ---------------- weight transform: OIHW fp32 -> [tap][co][ci] bf16 ----------------
__global__ __launch_bounds__(256) void wxform_k(const float* __restrict__ w,
                                                ushort* __restrict__ wb, int cout) {
  int i = blockIdx.x * 256 + threadIdx.x;
  int tot = cout * 64 * 9;
  if (i >= tot) return;
  int co = i / (64 * 9);
  int r = i % (64 * 9);
  int ci = r / 9, tap = r % 9;
  wb[(tap * cout + co) * 64 + ci] = f2bf(w[i]);
}

// ---------------- conv1x1 + bias + relu -> bf16 NHWC padded (halo 1) ----------------
template <int CIN>
__global__ __launch_bounds__(256) void conv1x1_nhwc_k(
    const float* __restrict__ srcA, const float* __restrict__ srcB,
    const float* __restrict__ w, const float* __restrict__ bias,
    ushort* __restrict__ out) {
  __shared__ float wt[CIN * 64];
  for (int i = threadIdx.x; i < CIN * 64; i += 256) {
    int ci = i >> 6, co = i & 63;
    wt[i] = w[co * CIN + ci];
  }
  __syncthreads();
  int p = blockIdx.x * 256 + threadIdx.x;
  int bb = p / HW, pix = p % HW;
  const float* src =
      (bb < Bz ? srcA + (size_t)bb * CIN * HW : srcB + (size_t)(bb - Bz) * CIN * HW) + pix;
  float acc[64];
#pragma unroll
  for (int co = 0; co < 64; co++) acc[co] = bias[co];
  for (int ci = 0; ci < CIN; ci++) {
    float x = src[(size_t)ci * HW];
    const float4* w4 = (const float4*)&wt[ci * 64];
#pragma unroll
    for (int q = 0; q < 16; q++) {
      float4 wv = w4[q];
      acc[4 * q + 0] += x * wv.x;
      acc[4 * q + 1] += x * wv.y;
      acc[4 * q + 2] += x * wv.z;
      acc[4 * q + 3] += x * wv.w;
    }
  }
  int y = pix / W, x = pix % W;
  ushort* o = out + ((size_t)bb * PPLANE + (size_t)(y + 1) * PW + (x + 1)) * 64;
  uint4* o4 = (uint4*)o;
#pragma unroll
  for (int g = 0; g < 8; g++) {
    unsigned u0 = (unsigned)f2bf(fmaxf(acc[8 * g + 0], 0.f)) |
                  ((unsigned)f2bf(fmaxf(acc[8 * g + 1], 0.f)) << 16);
    unsigned u1 = (unsigned)f2bf(fmaxf(acc[8 * g + 2], 0.f)) |
                  ((unsigned)f2bf(fmaxf(acc[8 * g + 3], 0.f)) << 16);
    unsigned u2 = (unsigned)f2bf(fmaxf(acc[8 * g + 4], 0.f)) |
                  ((unsigned)f2bf(fmaxf(acc[8 * g + 5], 0.f)) << 16);
    unsigned u3 = (unsigned)f2bf(fmaxf(acc[8 * g + 6], 0.f)) |
                  ((unsigned)f2bf(fmaxf(acc[8 * g + 7], 0.f)) << 16);
    o4[g] = uint4{u0, u1, u2, u3};
  }
}

// ---------------- conv3x3 via bf16 MFMA implicit GEMM ----------------
template <int COUT, bool NHWC>
__global__ __launch_bounds__(256) void conv3x3_mfma_k(
    const ushort* __restrict__ in, const ushort* __restrict__ wb,
    const float* __restrict__ bias, float* __restrict__ outf,
    ushort* __restrict__ outh) {
  constexpr int NF = COUT / 16;
  __shared__ ushort As[272 * 72];
  __shared__ ushort Bs[3 * COUT * 64];
  const int tile = blockIdx.x, img = blockIdx.y;
  const int pp0 = PW + tile * 256;
  const int tid = threadIdx.x, wave = tid >> 6, lane = tid & 63;
  const int lm = lane & 15, lq = lane >> 4;
  const ushort* inb = in + (size_t)img * PPLANE * 64;

  f32x4 acc[4][NF];
#pragma unroll
  for (int mf = 0; mf < 4; mf++)
#pragma unroll
    for (int nf = 0; nf < NF; nf++) acc[mf][nf] = f32x4{0.f, 0.f, 0.f, 0.f};

  for (int dy = 0; dy < 3; dy++) {
    __syncthreads();
    long abase = ((long)pp0 + (long)(dy - 1) * PW - 8) * 64;
    for (int i = tid; i < 272 * 8; i += 256) {
      int m = i >> 3, kseg = i & 7;
      uint4 v = *(const uint4*)(inb + abase + (long)m * 64 + kseg * 8);
      *(uint4*)&As[m * 72 + kseg * 8] = v;
    }
    for (int i = tid; i < 3 * COUT * 8; i += 256) {
      int dx = i / (COUT * 8);
      int r = i % (COUT * 8);
      int co = r >> 3, kseg = r & 7;
      uint4 v = *(const uint4*)(wb + (((size_t)(dy * 3 + dx) * COUT + co) << 6) + kseg * 8);
      *(uint4*)&Bs[(dx * COUT + co) * 64 + ((kseg ^ (co & 7)) * 8)] = v;
    }
    __syncthreads();
#pragma unroll
    for (int dx = 0; dx < 3; dx++) {
#pragma unroll
      for (int kc = 0; kc < 2; kc++) {
        bf16x8 bfr[NF];
#pragma unroll
        for (int nf = 0; nf < NF; nf++) {
          int n = nf * 16 + lm;
          int kb = kc * 4 + lq;
          bfr[nf] = *(const bf16x8*)&Bs[(dx * COUT + n) * 64 + ((kb ^ (n & 7)) * 8)];
        }
#pragma unroll
        for (int mf = 0; mf < 4; mf++) {
          int mo = (wave * 4 + mf) * 16 + lm;
          bf16x8 afr = *(const bf16x8*)&As[(mo + dx + 7) * 72 + kc * 32 + lq * 8];
#pragma unroll
          for (int nf = 0; nf < NF; nf++)
            acc[mf][nf] = __builtin_amdgcn_mfma_f32_16x16x32_bf16(afr, bfr[nf],
                                                                  acc[mf][nf], 0, 0, 0);
        }
      }
    }
  }
  float bv[NF];
#pragma unroll
  for (int nf = 0; nf < NF; nf++) bv[nf] = bias[nf * 16 + lm];
#pragma unroll
  for (int mf = 0; mf < 4; mf++) {
#pragma unroll
    for (int nf = 0; nf < NF; nf++) {
      int co = nf * 16 + lm;
#pragma unroll
      for (int r = 0; r < 4; r++) {
        int mo = pp0 + (wave * 4 + mf) * 16 + lq * 4 + r;
        int py = mo / PW, px = mo % PW;
        if (py >= 1 && py <= H && px >= 1 && px <= W) {
          float v = fmaxf(acc[mf][nf][r] + bv[nf], 0.f);
          if (NHWC) {
            ushort* eo = outh + (size_t)img * EPL * 64;
            eo[(((size_t)(py + 3)) * EPW + (px + 3)) * 64 + co] = f2bf(v);
          } else {
            outf[((size_t)img * COUT + co) * HW + (py - 1) * W + (px - 1)] = v;
          }
        }
      }
    }
  }
}

// ---------------- correlation via banded MFMA + fused softmax ----------------
// output layout: wgt[b][k][y*W+x] bf16 (planar per tap, k = di*9+dj)
__global__ __launch_bounds__(128) void corr_mfma_k(
    const ushort* __restrict__ e, ushort* __restrict__ wgt) {
  __shared__ float S[2 * 16 * 91];
  const int wave = threadIdx.x >> 6, lane = threadIdx.x & 63;
  const int x0 = blockIdx.x * 16;
  const int y = blockIdx.y * 2 + wave;
  const int b = blockIdx.z;
  const int nl = lane & 15, kq = lane >> 4;
  const ushort* es = e + (size_t)b * EPL * 64;
  const ushort* ec = e + (size_t)(b + 4) * EPL * 64;
  size_t abase = ((size_t)(y + 4) * EPW + (size_t)(4 + x0 + nl)) * 64 + kq * 8;
  bf16x8 afr0 = *(const bf16x8*)(es + abase);
  bf16x8 afr1 = *(const bf16x8*)(es + abase + 32);
  float* Sw = &S[wave * 16 * 91];
  for (int di = 0; di < 9; di++) {
    const ushort* erow = ec + ((size_t)(y + di) * EPW + x0) * 64;
#pragma unroll
    for (int nh = 0; nh < 2; nh++) {
      f32x4 g = f32x4{0.f, 0.f, 0.f, 0.f};
      const ushort* bp = erow + (size_t)(nh * 16 + nl) * 64 + kq * 8;
      bf16x8 b0 = *(const bf16x8*)(bp);
      bf16x8 b1 = *(const bf16x8*)(bp + 32);
      g = __builtin_amdgcn_mfma_f32_16x16x32_bf16(afr0, b0, g, 0, 0, 0);
      g = __builtin_amdgcn_mfma_f32_16x16x32_bf16(afr1, b1, g, 0, 0, 0);
      int q = nh * 16 + nl;
#pragma unroll
      for (int r = 0; r < 4; r++) {
        int m = kq * 4 + r;
        int s = q - m;
        if (s >= 0 && s <= 8) Sw[m * 91 + di * 9 + s] = g[r];
      }
    }
  }
  int px = lane >> 2, lg = lane & 3;
  float* Sp = &Sw[px * 91];
  float mx = -1e30f;
  for (int k = lg; k < 81; k += 4) mx = fmaxf(mx, Sp[k]);
  mx = fmaxf(mx, __shfl_xor(mx, 1));
  mx = fmaxf(mx, __shfl_xor(mx, 2));
  float sum = 0.f;
  for (int k = lg; k < 81; k += 4) {
    float t = expf(Sp[k] - mx);
    Sp[k] = t;
    sum += t;
  }
  sum += __shfl_xor(sum, 1);
  sum += __shfl_xor(sum, 2);
  float rinv = 1.f / sum;
  if (x0 + px < W) {
    ushort* wp = wgt + (size_t)b * 81 * HW + (size_t)y * W + x0 + px;
    for (int k = lg; k < 81; k += 4) wp[(size_t)k * HW] = f2bf(Sp[k] * rinv);
  }
}

// ---------------- align: direct VALU sliding-window weighted gather ----------------
// out[c][y][x] = sum_{di,dj} w[y][x][di*9+dj] * fs[c][y+di-4][x+dj-4]
// tile 16 wide x 8 rows; thread = (xq 0..3: 4 px, yy 0..7, cl 0..7: 4 channels);
// 4 rounds x 32 channels. LDS: W [81][128] bf16 (20.25K) + F [32][16][28] f32 (56K)
// -> 78KB => 2 blocks/CU. F stride 28: b128 granule classes (xq-yy)%8 land 8-even.
__global__ __launch_bounds__(256, 2) void align_valu_k(
    const ushort* __restrict__ wgt, const float* __restrict__ fs,
    float* __restrict__ out) {
  __shared__ ushort Ws[81 * 128];
  __shared__ float Fs[32 * 448];
  const int tid = threadIdx.x;
  // grid (25,13,4): x = y-tile (fast-varying so y-neighbors share XCD L2 halo),
  // y = x-tile, z = b.  Bijective XCD swizzle: nwg=1300, q=162, r=4.
  int orig = blockIdx.x + 25 * (blockIdx.y + 13 * blockIdx.z);
  int xcd = orig & 7, idx = orig >> 3;
  int wgid = (xcd < 4 ? xcd * 163 : 652 + (xcd - 4) * 162) + idx;
  int by = wgid % 25;
  int t2 = wgid / 25;
  int bx = t2 % 13;
  int b = t2 / 13;
  const int x0 = bx * 16, y0 = by * 8;

  // stage weights transposed: Ws[k][px], px = row*16+col within tile
  {
    const ushort* wb = wgt + (size_t)b * 81 * HW;
    for (int i = tid; i < 81 * 128; i += 256) {
      int k = i >> 7, px = i & 127;
      int gy = y0 + (px >> 4);
      int gx = x0 + (px & 15);
      if (gx > W - 1) gx = W - 1; // clamp for partial last x-tile (values unused)
      Ws[i] = wb[(size_t)k * HW + gy * W + gx];
    }
  }
  const int xq = tid & 3, yy = (tid >> 2) & 7, cl = tid >> 5;
  const int pxw = yy * 16 + xq * 4;
  const int xb = x0 + xq * 4;
  for (int r = 0; r < 4; ++r) {
    if (r) __syncthreads();
    // stage F: 32 channels x 16 rows x 24 cols f32 (halo 4), row stride 28
    {
      const float* fb = fs + ((size_t)b * 128 + r * 32) * HW;
      for (int i = tid; i < 32 * 384; i += 256) {
        int cc = i / 384, rem = i % 384;
        int row = rem / 24, col = rem % 24;
        int gy = y0 - 4 + row, gx = x0 - 4 + col;
        float v = 0.f;
        if (gy >= 0 && gy < H && gx >= 0 && gx < W)
          v = fb[(size_t)cc * HW + gy * W + gx];
        Fs[cc * 448 + row * 28 + col] = v;
      }
    }
    __syncthreads();
    float acc[4][4];
#pragma unroll
    for (int j = 0; j < 4; j++)
#pragma unroll
      for (int p = 0; p < 4; p++) acc[j][p] = 0.f;
    for (int di = 0; di < 9; ++di) {
      float fr[4][12];
#pragma unroll
      for (int j = 0; j < 4; ++j) {
        const float4* fp =
            (const float4*)&Fs[(cl * 4 + j) * 448 + (yy + di) * 28 + xq * 4];
        float4 f0 = fp[0], f1 = fp[1], f2 = fp[2];
        fr[j][0] = f0.x; fr[j][1] = f0.y; fr[j][2] = f0.z; fr[j][3] = f0.w;
        fr[j][4] = f1.x; fr[j][5] = f1.y; fr[j][6] = f1.z; fr[j][7] = f1.w;
        fr[j][8] = f2.x; fr[j][9] = f2.y; fr[j][10] = f2.z; fr[j][11] = f2.w;
      }
#pragma unroll
      for (int dj = 0; dj < 9; ++dj) {
        uint2 wv = *(const uint2*)&Ws[(di * 9 + dj) * 128 + pxw];
        float w0 = __uint_as_float(wv.x << 16);
        float w1 = __uint_as_float(wv.x & 0xffff0000u);
        float w2 = __uint_as_float(wv.y << 16);
        float w3 = __uint_as_float(wv.y & 0xffff0000u);
#pragma unroll
        for (int j = 0; j < 4; ++j) {
          acc[j][0] += w0 * fr[j][dj + 0];
          acc[j][1] += w1 * fr[j][dj + 1];
          acc[j][2] += w2 * fr[j][dj + 2];
          acc[j][3] += w3 * fr[j][dj + 3];
        }
      }
    }
    if (xb < W) {
#pragma unroll
      for (int j = 0; j < 4; ++j) {
        int c = r * 32 + cl * 4 + j;
        *(float4*)&out[((size_t)b * 128 + c) * HW + (size_t)(y0 + yy) * W + xb] =
            float4{acc[j][0], acc[j][1], acc[j][2], acc[j][3]};
      }
    }
  }
}

// ---------------- ag3 conv1x1 (32->1) + relu + 2-way softmax + blend ----------------
__global__ __launch_bounds__(256) void final_k(
    const float* __restrict__ a2, const float* __restrict__ w3,
    const float* __restrict__ b3, const float* __restrict__ alignb,
    const float* __restrict__ fcur, float* __restrict__ out) {
  int p = blockIdx.x * 256 + threadIdx.x;
  int bb = p / HW, pix = p % HW;
  const float* aS = a2 + (size_t)bb * 32 * HW + pix;
  const float* aC = a2 + (size_t)(bb + Bz) * 32 * HW + pix;
  float s0 = b3[0], s1 = b3[0];
#pragma unroll
  for (int c = 0; c < 32; c++) {
    float wv = w3[c];
    s0 += wv * aS[(size_t)c * HW];
    s1 += wv * aC[(size_t)c * HW];
  }
  s0 = fmaxf(s0, 0.f);
  s1 = fmaxf(s1, 0.f);
  float m = fmaxf(s0, s1);
  float e0 = expf(s0 - m), e1 = expf(s1 - m);
  float inv = 1.f / (e0 + e1);
  float p0 = e0 * inv, p1 = e1 * inv;
  const float* al = alignb + (size_t)bb * 128 * HW + pix;
  const float* fc = fcur + (size_t)bb * 128 * HW + pix;
  float* o = out + (size_t)bb * 128 * HW + pix;
#pragma unroll 4
  for (int c = 0; c < 128; c++)
    o[(size_t)c * HW] = p0 * al[(size_t)c * HW] + p1 * fc[(size_t)c * HW];
}

extern "C" void kernel_launch(void* const* d_in, const int* in_sizes, int n_in,
                              void* d_out, int out_size, void* d_ws, size_t ws_size,
                              hipStream_t stream) {
  const float* fsel = (const float*)d_in[0];
  const float* fcur = (const float*)d_in[1];
  const float* ec1_w = (const float*)d_in[2];
  const float* ec1_b = (const float*)d_in[3];
  const float* ec2_w = (const float*)d_in[4];
  const float* ec2_b = (const float*)d_in[5];
  const float* ag1_w = (const float*)d_in[6];
  const float* ag1_b = (const float*)d_in[7];
  const float* ag2_w = (const float*)d_in[8];
  const float* ag2_b = (const float*)d_in[9];
  const float* ag3_w = (const float*)d_in[10];
  const float* ag3_b = (const float*)d_in[11];

  char* ws = (char*)d_ws;
  size_t off = 4096;
  ushort* padbuf = (ushort*)(ws + off);
  size_t padbuf_bytes = (size_t)8 * PPLANE * 64 * 2;
  off += padbuf_bytes;
  ushort* epad = (ushort*)(ws + off);
  size_t epad_bytes = (size_t)8 * EPL * 64 * 2;
  off += epad_bytes + 4096;
  ushort* wgtb = (ushort*)(ws + off);
  off += (size_t)4 * 81 * HW * 2 + 4096;
  float* alignb = (float*)(ws + off);
  off += (size_t)4 * 128 * HW * 4;
  ushort* wb1 = (ushort*)(ws + off);
  off += 9 * 64 * 64 * 2;
  ushort* wb2 = (ushort*)(ws + off);
  off += 9 * 32 * 64 * 2;
  float* a2 = (float*)epad;
  float* outp = (float*)d_out;

  dim3 blk(256);
  const int MTILES = (200 * PW + 255) / 256; // 163

  wxform_k<<<(9 * 64 * 64 + 255) / 256, blk, 0, stream>>>(ec2_w, wb1, 64);
  wxform_k<<<(9 * 32 * 64 + 255) / 256, blk, 0, stream>>>(ag2_w, wb2, 32);
  {
    int nz = (int)((padbuf_bytes + epad_bytes) / 16);
    zero_k<<<(nz + 255) / 256, blk, 0, stream>>>((uint4*)padbuf, nz);
  }
  conv1x1_nhwc_k<128><<<1250, blk, 0, stream>>>(fsel, fcur, ec1_w, ec1_b, padbuf);
  conv3x3_mfma_k<64, true><<<dim3(MTILES, 8), blk, 0, stream>>>(
      padbuf, wb1, ec2_b, nullptr, epad);
  corr_mfma_k<<<dim3(13, 100, 4), dim3(128), 0, stream>>>(epad, wgtb);
  align_valu_k<<<dim3(25, 13, 4), blk, 0, stream>>>(wgtb, fsel, alignb);
  conv1x1_nhwc_k<128><<<1250, blk, 0, stream>>>(alignb, fcur, ag1_w, ag1_b, padbuf);
  conv3x3_mfma_k<32, false><<<dim3(MTILES, 8), blk, 0, stream>>>(
      padbuf, wb2, ag2_b, a2, nullptr);
  final_k<<<625, blk, 0, stream>>>(a2, ag3_w, ag3_b, alignb, fcur, outp);
}

// Round 2
// 1027.524 us; speedup vs baseline: 1.0530x; 1.0530x over previous
//
#include <hip/hip_runtime.h>

namespace {
constexpr int H = 200, W = 200, HW = H * W;
constexpr int Bz = 4;
constexpr int PW = 208, PH = 202, PPLANE = PW * PH; // conv1x1 pad geometry (halo 1)
constexpr int EPW = 208, EPH = 208, EPL = EPW * EPH; // e-pad geometry (halo 4)
}

typedef __attribute__((ext_vector_type(8))) short bf16x8;
typedef __attribute__((ext_vector_type(4))) float f32x4;

__device__ inline ushort f2bf(float f) {
  unsigned u = __float_as_uint(f);
  u += 0x7fffu + ((u >> 16) & 1u);
  return (ushort)(u >> 16);
}

// ---------------- zero fill ----------------
__global__ __launch_bounds__(256) void zero_k(uint4* __restrict__ p, int n) {
  int i = blockIdx.x * 256 + threadIdx.x;
  if (i < n) p[i] = uint4{0u, 0u, 0u, 0u};
}

// ---------------- weight transform: OIHW fp32 -> [tap][co][ci] bf16 ----------------
__global__ __launch_bounds__(256) void wxform_k(const float* __restrict__ w,
                                                ushort* __restrict__ wb, int cout) {
  int i = blockIdx.x * 256 + threadIdx.x;
  int tot = cout * 64 * 9;
  if (i >= tot) return;
  int co = i / (64 * 9);
  int r = i % (64 * 9);
  int ci = r / 9, tap = r % 9;
  wb[(tap * cout + co) * 64 + ci] = f2bf(w[i]);
}

// ---------------- conv1x1 + bias + relu -> bf16 NHWC padded (halo 1) ----------------
template <int CIN>
__global__ __launch_bounds__(256) void conv1x1_nhwc_k(
    const float* __restrict__ srcA, const float* __restrict__ srcB,
    const float* __restrict__ w, const float* __restrict__ bias,
    ushort* __restrict__ out) {
  __shared__ float wt[CIN * 64];
  for (int i = threadIdx.x; i < CIN * 64; i += 256) {
    int ci = i >> 6, co = i & 63;
    wt[i] = w[co * CIN + ci];
  }
  __syncthreads();
  int p = blockIdx.x * 256 + threadIdx.x;
  int bb = p / HW, pix = p % HW;
  const float* src =
      (bb < Bz ? srcA + (size_t)bb * CIN * HW : srcB + (size_t)(bb - Bz) * CIN * HW) + pix;
  float acc[64];
#pragma unroll
  for (int co = 0; co < 64; co++) acc[co] = bias[co];
  for (int ci = 0; ci < CIN; ci++) {
    float x = src[(size_t)ci * HW];
    const float4* w4 = (const float4*)&wt[ci * 64];
#pragma unroll
    for (int q = 0; q < 16; q++) {
      float4 wv = w4[q];
      acc[4 * q + 0] += x * wv.x;
      acc[4 * q + 1] += x * wv.y;
      acc[4 * q + 2] += x * wv.z;
      acc[4 * q + 3] += x * wv.w;
    }
  }
  int y = pix / W, x = pix % W;
  ushort* o = out + ((size_t)bb * PPLANE + (size_t)(y + 1) * PW + (x + 1)) * 64;
  uint4* o4 = (uint4*)o;
#pragma unroll
  for (int g = 0; g < 8; g++) {
    unsigned u0 = (unsigned)f2bf(fmaxf(acc[8 * g + 0], 0.f)) |
                  ((unsigned)f2bf(fmaxf(acc[8 * g + 1], 0.f)) << 16);
    unsigned u1 = (unsigned)f2bf(fmaxf(acc[8 * g + 2], 0.f)) |
                  ((unsigned)f2bf(fmaxf(acc[8 * g + 3], 0.f)) << 16);
    unsigned u2 = (unsigned)f2bf(fmaxf(acc[8 * g + 4], 0.f)) |
                  ((unsigned)f2bf(fmaxf(acc[8 * g + 5], 0.f)) << 16);
    unsigned u3 = (unsigned)f2bf(fmaxf(acc[8 * g + 6], 0.f)) |
                  ((unsigned)f2bf(fmaxf(acc[8 * g + 7], 0.f)) << 16);
    o4[g] = uint4{u0, u1, u2, u3};
  }
}

// ---------------- conv3x3 via bf16 MFMA implicit GEMM ----------------
template <int COUT, bool NHWC>
__global__ __launch_bounds__(256) void conv3x3_mfma_k(
    const ushort* __restrict__ in, const ushort* __restrict__ wb,
    const float* __restrict__ bias, float* __restrict__ outf,
    ushort* __restrict__ outh) {
  constexpr int NF = COUT / 16;
  __shared__ ushort As[272 * 72];
  __shared__ ushort Bs[3 * COUT * 64];
  const int tile = blockIdx.x, img = blockIdx.y;
  const int pp0 = PW + tile * 256;
  const int tid = threadIdx.x, wave = tid >> 6, lane = tid & 63;
  const int lm = lane & 15, lq = lane >> 4;
  const ushort* inb = in + (size_t)img * PPLANE * 64;

  f32x4 acc[4][NF];
#pragma unroll
  for (int mf = 0; mf < 4; mf++)
#pragma unroll
    for (int nf = 0; nf < NF; nf++) acc[mf][nf] = f32x4{0.f, 0.f, 0.f, 0.f};

  for (int dy = 0; dy < 3; dy++) {
    __syncthreads();
    long abase = ((long)pp0 + (long)(dy - 1) * PW - 8) * 64;
    for (int i = tid; i < 272 * 8; i += 256) {
      int m = i >> 3, kseg = i & 7;
      uint4 v = *(const uint4*)(inb + abase + (long)m * 64 + kseg * 8);
      *(uint4*)&As[m * 72 + kseg * 8] = v;
    }
    for (int i = tid; i < 3 * COUT * 8; i += 256) {
      int dx = i / (COUT * 8);
      int r = i % (COUT * 8);
      int co = r >> 3, kseg = r & 7;
      uint4 v = *(const uint4*)(wb + (((size_t)(dy * 3 + dx) * COUT + co) << 6) + kseg * 8);
      *(uint4*)&Bs[(dx * COUT + co) * 64 + ((kseg ^ (co & 7)) * 8)] = v;
    }
    __syncthreads();
#pragma unroll
    for (int dx = 0; dx < 3; dx++) {
#pragma unroll
      for (int kc = 0; kc < 2; kc++) {
        bf16x8 bfr[NF];
#pragma unroll
        for (int nf = 0; nf < NF; nf++) {
          int n = nf * 16 + lm;
          int kb = kc * 4 + lq;
          bfr[nf] = *(const bf16x8*)&Bs[(dx * COUT + n) * 64 + ((kb ^ (n & 7)) * 8)];
        }
#pragma unroll
        for (int mf = 0; mf < 4; mf++) {
          int mo = (wave * 4 + mf) * 16 + lm;
          bf16x8 afr = *(const bf16x8*)&As[(mo + dx + 7) * 72 + kc * 32 + lq * 8];
#pragma unroll
          for (int nf = 0; nf < NF; nf++)
            acc[mf][nf] = __builtin_amdgcn_mfma_f32_16x16x32_bf16(afr, bfr[nf],
                                                                  acc[mf][nf], 0, 0, 0);
        }
      }
    }
  }
  float bv[NF];
#pragma unroll
  for (int nf = 0; nf < NF; nf++) bv[nf] = bias[nf * 16 + lm];
#pragma unroll
  for (int mf = 0; mf < 4; mf++) {
#pragma unroll
    for (int nf = 0; nf < NF; nf++) {
      int co = nf * 16 + lm;
#pragma unroll
      for (int r = 0; r < 4; r++) {
        int mo = pp0 + (wave * 4 + mf) * 16 + lq * 4 + r;
        int py = mo / PW, px = mo % PW;
        if (py >= 1 && py <= H && px >= 1 && px <= W) {
          float v = fmaxf(acc[mf][nf][r] + bv[nf], 0.f);
          if (NHWC) {
            ushort* eo = outh + (size_t)img * EPL * 64;
            eo[(((size_t)(py + 3)) * EPW + (px + 3)) * 64 + co] = f2bf(v);
          } else {
            outf[((size_t)img * COUT + co) * HW + (py - 1) * W + (px - 1)] = v;
          }
        }
      }
    }
  }
}

// ---------------- correlation via banded MFMA + fused softmax ----------------
// output layout: wgt[b][k][y*W+x] bf16 (planar per tap, k = di*9+dj)
__global__ __launch_bounds__(128) void corr_mfma_k(
    const ushort* __restrict__ e, ushort* __restrict__ wgt) {
  __shared__ float S[2 * 16 * 91];
  const int wave = threadIdx.x >> 6, lane = threadIdx.x & 63;
  const int x0 = blockIdx.x * 16;
  const int y = blockIdx.y * 2 + wave;
  const int b = blockIdx.z;
  const int nl = lane & 15, kq = lane >> 4;
  const ushort* es = e + (size_t)b * EPL * 64;
  const ushort* ec = e + (size_t)(b + 4) * EPL * 64;
  size_t abase = ((size_t)(y + 4) * EPW + (size_t)(4 + x0 + nl)) * 64 + kq * 8;
  bf16x8 afr0 = *(const bf16x8*)(es + abase);
  bf16x8 afr1 = *(const bf16x8*)(es + abase + 32);
  float* Sw = &S[wave * 16 * 91];
  for (int di = 0; di < 9; di++) {
    const ushort* erow = ec + ((size_t)(y + di) * EPW + x0) * 64;
#pragma unroll
    for (int nh = 0; nh < 2; nh++) {
      f32x4 g = f32x4{0.f, 0.f, 0.f, 0.f};
      const ushort* bp = erow + (size_t)(nh * 16 + nl) * 64 + kq * 8;
      bf16x8 b0 = *(const bf16x8*)(bp);
      bf16x8 b1 = *(const bf16x8*)(bp + 32);
      g = __builtin_amdgcn_mfma_f32_16x16x32_bf16(afr0, b0, g, 0, 0, 0);
      g = __builtin_amdgcn_mfma_f32_16x16x32_bf16(afr1, b1, g, 0, 0, 0);
      int q = nh * 16 + nl;
#pragma unroll
      for (int r = 0; r < 4; r++) {
        int m = kq * 4 + r;
        int s = q - m;
        if (s >= 0 && s <= 8) Sw[m * 91 + di * 9 + s] = g[r];
      }
    }
  }
  int px = lane >> 2, lg = lane & 3;
  float* Sp = &Sw[px * 91];
  float mx = -1e30f;
  for (int k = lg; k < 81; k += 4) mx = fmaxf(mx, Sp[k]);
  mx = fmaxf(mx, __shfl_xor(mx, 1));
  mx = fmaxf(mx, __shfl_xor(mx, 2));
  float sum = 0.f;
  for (int k = lg; k < 81; k += 4) {
    float t = expf(Sp[k] - mx);
    Sp[k] = t;
    sum += t;
  }
  sum += __shfl_xor(sum, 1);
  sum += __shfl_xor(sum, 2);
  float rinv = 1.f / sum;
  if (x0 + px < W) {
    ushort* wp = wgt + (size_t)b * 81 * HW + (size_t)y * W + x0 + px;
    for (int k = lg; k < 81; k += 4) wp[(size_t)k * HW] = f2bf(Sp[k] * rinv);
  }
}

// ---------------- align: direct VALU sliding-window weighted gather ----------------
// out[c][y][x] = sum_{di,dj} w[y][x][di*9+dj] * fs[c][y+di-4][x+dj-4]
// tile 16 wide x 8 rows; thread = (xq 0..3: 4 px, yy 0..7, cl 0..7: 4 channels);
// 4 rounds x 32 channels. LDS: Ws [81][128] bf16 (20.25K) + Fs [32][16][24] f32 (48K).
// Fs row stride 24 words (== -8 mod 32): quarter-wave b128 start classes
// {0,1,2,3},{6,7,0,1},{4,5,6,7},{2,3,4,5} -> exactly 2 lanes/4-bank group =
// b128 minimum (conflict-free). R1 bug: stride 28 (== -4 mod 32) collided with
// the +4 xq step -> 4-way conflicts, 7.7e7 conflict cycles, LDS-pipe bound.
__global__ __launch_bounds__(256, 2) void align_valu_k(
    const ushort* __restrict__ wgt, const float* __restrict__ fs,
    float* __restrict__ out) {
  __shared__ ushort Ws[81 * 128];
  __shared__ float Fs[32 * 384];
  const int tid = threadIdx.x;
  // grid (25,13,4): x = y-tile (fast-varying so y-neighbors share XCD L2 halo),
  // y = x-tile, z = b.  Bijective XCD swizzle: nwg=1300, q=162, r=4.
  int orig = blockIdx.x + 25 * (blockIdx.y + 13 * blockIdx.z);
  int xcd = orig & 7, idx = orig >> 3;
  int wgid = (xcd < 4 ? xcd * 163 : 652 + (xcd - 4) * 162) + idx;
  int by = wgid % 25;
  int t2 = wgid / 25;
  int bx = t2 % 13;
  int b = t2 / 13;
  const int x0 = bx * 16, y0 = by * 8;

  // stage weights transposed: Ws[k][px], px = row*16+col within tile
  {
    const ushort* wb = wgt + (size_t)b * 81 * HW;
    for (int i = tid; i < 81 * 128; i += 256) {
      int k = i >> 7, px = i & 127;
      int gy = y0 + (px >> 4);
      int gx = x0 + (px & 15);
      if (gx > W - 1) gx = W - 1; // clamp for partial last x-tile (values unused)
      Ws[i] = wb[(size_t)k * HW + gy * W + gx];
    }
  }
  const int xq = tid & 3, yy = (tid >> 2) & 7, cl = tid >> 5;
  const int pxw = yy * 16 + xq * 4;
  const int xb = x0 + xq * 4;
  for (int r = 0; r < 4; ++r) {
    if (r) __syncthreads();
    // stage F: 32 channels x 16 rows x 24 cols f32 (halo 4), row stride 24
    {
      const float* fb = fs + ((size_t)b * 128 + r * 32) * HW;
      for (int i = tid; i < 32 * 384; i += 256) {
        int cc = i / 384, rem = i % 384;
        int row = rem / 24, col = rem % 24;
        int gy = y0 - 4 + row, gx = x0 - 4 + col;
        float v = 0.f;
        if (gy >= 0 && gy < H && gx >= 0 && gx < W)
          v = fb[(size_t)cc * HW + gy * W + gx];
        Fs[cc * 384 + row * 24 + col] = v;
      }
    }
    __syncthreads();
    float acc[4][4];
#pragma unroll
    for (int j = 0; j < 4; j++)
#pragma unroll
      for (int p = 0; p < 4; p++) acc[j][p] = 0.f;
    for (int di = 0; di < 9; ++di) {
      float fr[4][12];
#pragma unroll
      for (int j = 0; j < 4; ++j) {
        const float4* fp =
            (const float4*)&Fs[(cl * 4 + j) * 384 + (yy + di) * 24 + xq * 4];
        float4 f0 = fp[0], f1 = fp[1], f2 = fp[2];
        fr[j][0] = f0.x; fr[j][1] = f0.y; fr[j][2] = f0.z; fr[j][3] = f0.w;
        fr[j][4] = f1.x; fr[j][5] = f1.y; fr[j][6] = f1.z; fr[j][7] = f1.w;
        fr[j][8] = f2.x; fr[j][9] = f2.y; fr[j][10] = f2.z; fr[j][11] = f2.w;
      }
#pragma unroll
      for (int dj = 0; dj < 9; ++dj) {
        uint2 wv = *(const uint2*)&Ws[(di * 9 + dj) * 128 + pxw];
        float w0 = __uint_as_float(wv.x << 16);
        float w1 = __uint_as_float(wv.x & 0xffff0000u);
        float w2 = __uint_as_float(wv.y << 16);
        float w3 = __uint_as_float(wv.y & 0xffff0000u);
#pragma unroll
        for (int j = 0; j < 4; ++j) {
          acc[j][0] += w0 * fr[j][dj + 0];
          acc[j][1] += w1 * fr[j][dj + 1];
          acc[j][2] += w2 * fr[j][dj + 2];
          acc[j][3] += w3 * fr[j][dj + 3];
        }
      }
    }
    if (xb < W) {
#pragma unroll
      for (int j = 0; j < 4; ++j) {
        int c = r * 32 + cl * 4 + j;
        *(float4*)&out[((size_t)b * 128 + c) * HW + (size_t)(y0 + yy) * W + xb] =
            float4{acc[j][0], acc[j][1], acc[j][2], acc[j][3]};
      }
    }
  }
}

// ---------------- ag3 conv1x1 (32->1) + relu + 2-way softmax + blend ----------------
__global__ __launch_bounds__(256) void final_k(
    const float* __restrict__ a2, const float* __restrict__ w3,
    const float* __restrict__ b3, const float* __restrict__ alignb,
    const float* __restrict__ fcur, float* __restrict__ out) {
  int p = blockIdx.x * 256 + threadIdx.x;
  int bb = p / HW, pix = p % HW;
  const float* aS = a2 + (size_t)bb * 32 * HW + pix;
  const float* aC = a2 + (size_t)(bb + Bz) * 32 * HW + pix;
  float s0 = b3[0], s1 = b3[0];
#pragma unroll
  for (int c = 0; c < 32; c++) {
    float wv = w3[c];
    s0 += wv * aS[(size_t)c * HW];
    s1 += wv * aC[(size_t)c * HW];
  }
  s0 = fmaxf(s0, 0.f);
  s1 = fmaxf(s1, 0.f);
  float m = fmaxf(s0, s1);
  float e0 = expf(s0 - m), e1 = expf(s1 - m);
  float inv = 1.f / (e0 + e1);
  float p0 = e0 * inv, p1 = e1 * inv;
  const float* al = alignb + (size_t)bb * 128 * HW + pix;
  const float* fc = fcur + (size_t)bb * 128 * HW + pix;
  float* o = out + (size_t)bb * 128 * HW + pix;
#pragma unroll 4
  for (int c = 0; c < 128; c++)
    o[(size_t)c * HW] = p0 * al[(size_t)c * HW] + p1 * fc[(size_t)c * HW];
}

extern "C" void kernel_launch(void* const* d_in, const int* in_sizes, int n_in,
                              void* d_out, int out_size, void* d_ws, size_t ws_size,
                              hipStream_t stream) {
  const float* fsel = (const float*)d_in[0];
  const float* fcur = (const float*)d_in[1];
  const float* ec1_w = (const float*)d_in[2];
  const float* ec1_b = (const float*)d_in[3];
  const float* ec2_w = (const float*)d_in[4];
  const float* ec2_b = (const float*)d_in[5];
  const float* ag1_w = (const float*)d_in[6];
  const float* ag1_b = (const float*)d_in[7];
  const float* ag2_w = (const float*)d_in[8];
  const float* ag2_b = (const float*)d_in[9];
  const float* ag3_w = (const float*)d_in[10];
  const float* ag3_b = (const float*)d_in[11];

  char* ws = (char*)d_ws;
  size_t off = 4096;
  ushort* padbuf = (ushort*)(ws + off);
  size_t padbuf_bytes = (size_t)8 * PPLANE * 64 * 2;
  off += padbuf_bytes;
  ushort* epad = (ushort*)(ws + off);
  size_t epad_bytes = (size_t)8 * EPL * 64 * 2;
  off += epad_bytes + 4096;
  ushort* wgtb = (ushort*)(ws + off);
  off += (size_t)4 * 81 * HW * 2 + 4096;
  float* alignb = (float*)(ws + off);
  off += (size_t)4 * 128 * HW * 4;
  ushort* wb1 = (ushort*)(ws + off);
  off += 9 * 64 * 64 * 2;
  ushort* wb2 = (ushort*)(ws + off);
  off += 9 * 32 * 64 * 2;
  float* a2 = (float*)epad;
  float* outp = (float*)d_out;

  dim3 blk(256);
  const int MTILES = (200 * PW + 255) / 256; // 163

  wxform_k<<<(9 * 64 * 64 + 255) / 256, blk, 0, stream>>>(ec2_w, wb1, 64);
  wxform_k<<<(9 * 32 * 64 + 255) / 256, blk, 0, stream>>>(ag2_w, wb2, 32);
  {
    int nz = (int)((padbuf_bytes + epad_bytes) / 16);
    zero_k<<<(nz + 255) / 256, blk, 0, stream>>>((uint4*)padbuf, nz);
  }
  conv1x1_nhwc_k<128><<<1250, blk, 0, stream>>>(fsel, fcur, ec1_w, ec1_b, padbuf);
  conv3x3_mfma_k<64, true><<<dim3(MTILES, 8), blk, 0, stream>>>(
      padbuf, wb1, ec2_b, nullptr, epad);
  corr_mfma_k<<<dim3(13, 100, 4), dim3(128), 0, stream>>>(epad, wgtb);
  align_valu_k<<<dim3(25, 13, 4), blk, 0, stream>>>(wgtb, fsel, alignb);
  conv1x1_nhwc_k<128><<<1250, blk, 0, stream>>>(alignb, fcur, ag1_w, ag1_b, padbuf);
  conv3x3_mfma_k<32, false><<<dim3(MTILES, 8), blk, 0, stream>>>(
      padbuf, wb2, ag2_b, a2, nullptr);
  final_k<<<625, blk, 0, stream>>>(a2, ag3_w, ag3_b, alignb, fcur, outp);
}

// Round 3
// 985.615 us; speedup vs baseline: 1.0978x; 1.0425x over previous
//
#include <hip/hip_runtime.h>

namespace {
constexpr int H = 200, W = 200, HW = H * W;
constexpr int Bz = 4;
constexpr int PW = 208, PH = 202, PPLANE = PW * PH; // conv1x1 pad geometry (halo 1)
constexpr int EPW = 208, EPH = 208, EPL = EPW * EPH; // e-pad geometry (halo 4)
}

typedef __attribute__((ext_vector_type(8))) short bf16x8;
typedef __attribute__((ext_vector_type(4))) float f32x4;

__device__ inline ushort f2bf(float f) {
  unsigned u = __float_as_uint(f);
  u += 0x7fffu + ((u >> 16) & 1u);
  return (ushort)(u >> 16);
}

// ---------------- zero fill ----------------
__global__ __launch_bounds__(256) void zero_k(uint4* __restrict__ p, int n) {
  int i = blockIdx.x * 256 + threadIdx.x;
  if (i < n) p[i] = uint4{0u, 0u, 0u, 0u};
}

// ---------------- weight transform: OIHW fp32 -> [tap][co][ci] bf16 ----------------
__global__ __launch_bounds__(256) void wxform_k(const float* __restrict__ w,
                                                ushort* __restrict__ wb, int cout) {
  int i = blockIdx.x * 256 + threadIdx.x;
  int tot = cout * 64 * 9;
  if (i >= tot) return;
  int co = i / (64 * 9);
  int r = i % (64 * 9);
  int ci = r / 9, tap = r % 9;
  wb[(tap * cout + co) * 64 + ci] = f2bf(w[i]);
}

// ---------------- conv1x1 + bias + relu -> bf16 NHWC padded (halo 1) ----------------
template <int CIN>
__global__ __launch_bounds__(256) void conv1x1_nhwc_k(
    const float* __restrict__ srcA, const float* __restrict__ srcB,
    const float* __restrict__ w, const float* __restrict__ bias,
    ushort* __restrict__ out) {
  __shared__ float wt[CIN * 64];
  for (int i = threadIdx.x; i < CIN * 64; i += 256) {
    int ci = i >> 6, co = i & 63;
    wt[i] = w[co * CIN + ci];
  }
  __syncthreads();
  int p = blockIdx.x * 256 + threadIdx.x;
  int bb = p / HW, pix = p % HW;
  const float* src =
      (bb < Bz ? srcA + (size_t)bb * CIN * HW : srcB + (size_t)(bb - Bz) * CIN * HW) + pix;
  float acc[64];
#pragma unroll
  for (int co = 0; co < 64; co++) acc[co] = bias[co];
  for (int ci = 0; ci < CIN; ci++) {
    float x = src[(size_t)ci * HW];
    const float4* w4 = (const float4*)&wt[ci * 64];
#pragma unroll
    for (int q = 0; q < 16; q++) {
      float4 wv = w4[q];
      acc[4 * q + 0] += x * wv.x;
      acc[4 * q + 1] += x * wv.y;
      acc[4 * q + 2] += x * wv.z;
      acc[4 * q + 3] += x * wv.w;
    }
  }
  int y = pix / W, x = pix % W;
  ushort* o = out + ((size_t)bb * PPLANE + (size_t)(y + 1) * PW + (x + 1)) * 64;
  uint4* o4 = (uint4*)o;
#pragma unroll
  for (int g = 0; g < 8; g++) {
    unsigned u0 = (unsigned)f2bf(fmaxf(acc[8 * g + 0], 0.f)) |
                  ((unsigned)f2bf(fmaxf(acc[8 * g + 1], 0.f)) << 16);
    unsigned u1 = (unsigned)f2bf(fmaxf(acc[8 * g + 2], 0.f)) |
                  ((unsigned)f2bf(fmaxf(acc[8 * g + 3], 0.f)) << 16);
    unsigned u2 = (unsigned)f2bf(fmaxf(acc[8 * g + 4], 0.f)) |
                  ((unsigned)f2bf(fmaxf(acc[8 * g + 5], 0.f)) << 16);
    unsigned u3 = (unsigned)f2bf(fmaxf(acc[8 * g + 6], 0.f)) |
                  ((unsigned)f2bf(fmaxf(acc[8 * g + 7], 0.f)) << 16);
    o4[g] = uint4{u0, u1, u2, u3};
  }
}

// ---------------- conv3x3 via bf16 MFMA implicit GEMM ----------------
template <int COUT, bool NHWC>
__global__ __launch_bounds__(256) void conv3x3_mfma_k(
    const ushort* __restrict__ in, const ushort* __restrict__ wb,
    const float* __restrict__ bias, float* __restrict__ outf,
    ushort* __restrict__ outh) {
  constexpr int NF = COUT / 16;
  __shared__ ushort As[272 * 72];
  __shared__ ushort Bs[3 * COUT * 64];
  const int tile = blockIdx.x, img = blockIdx.y;
  const int pp0 = PW + tile * 256;
  const int tid = threadIdx.x, wave = tid >> 6, lane = tid & 63;
  const int lm = lane & 15, lq = lane >> 4;
  const ushort* inb = in + (size_t)img * PPLANE * 64;

  f32x4 acc[4][NF];
#pragma unroll
  for (int mf = 0; mf < 4; mf++)
#pragma unroll
    for (int nf = 0; nf < NF; nf++) acc[mf][nf] = f32x4{0.f, 0.f, 0.f, 0.f};

  for (int dy = 0; dy < 3; dy++) {
    __syncthreads();
    long abase = ((long)pp0 + (long)(dy - 1) * PW - 8) * 64;
    for (int i = tid; i < 272 * 8; i += 256) {
      int m = i >> 3, kseg = i & 7;
      uint4 v = *(const uint4*)(inb + abase + (long)m * 64 + kseg * 8);
      *(uint4*)&As[m * 72 + kseg * 8] = v;
    }
    for (int i = tid; i < 3 * COUT * 8; i += 256) {
      int dx = i / (COUT * 8);
      int r = i % (COUT * 8);
      int co = r >> 3, kseg = r & 7;
      uint4 v = *(const uint4*)(wb + (((size_t)(dy * 3 + dx) * COUT + co) << 6) + kseg * 8);
      *(uint4*)&Bs[(dx * COUT + co) * 64 + ((kseg ^ (co & 7)) * 8)] = v;
    }
    __syncthreads();
#pragma unroll
    for (int dx = 0; dx < 3; dx++) {
#pragma unroll
      for (int kc = 0; kc < 2; kc++) {
        bf16x8 bfr[NF];
#pragma unroll
        for (int nf = 0; nf < NF; nf++) {
          int n = nf * 16 + lm;
          int kb = kc * 4 + lq;
          bfr[nf] = *(const bf16x8*)&Bs[(dx * COUT + n) * 64 + ((kb ^ (n & 7)) * 8)];
        }
#pragma unroll
        for (int mf = 0; mf < 4; mf++) {
          int mo = (wave * 4 + mf) * 16 + lm;
          bf16x8 afr = *(const bf16x8*)&As[(mo + dx + 7) * 72 + kc * 32 + lq * 8];
#pragma unroll
          for (int nf = 0; nf < NF; nf++)
            acc[mf][nf] = __builtin_amdgcn_mfma_f32_16x16x32_bf16(afr, bfr[nf],
                                                                  acc[mf][nf], 0, 0, 0);
        }
      }
    }
  }
  float bv[NF];
#pragma unroll
  for (int nf = 0; nf < NF; nf++) bv[nf] = bias[nf * 16 + lm];
#pragma unroll
  for (int mf = 0; mf < 4; mf++) {
#pragma unroll
    for (int nf = 0; nf < NF; nf++) {
      int co = nf * 16 + lm;
#pragma unroll
      for (int r = 0; r < 4; r++) {
        int mo = pp0 + (wave * 4 + mf) * 16 + lq * 4 + r;
        int py = mo / PW, px = mo % PW;
        if (py >= 1 && py <= H && px >= 1 && px <= W) {
          float v = fmaxf(acc[mf][nf][r] + bv[nf], 0.f);
          if (NHWC) {
            ushort* eo = outh + (size_t)img * EPL * 64;
            eo[(((size_t)(py + 3)) * EPW + (px + 3)) * 64 + co] = f2bf(v);
          } else {
            outf[((size_t)img * COUT + co) * HW + (py - 1) * W + (px - 1)] = v;
          }
        }
      }
    }
  }
}

// ---------------- correlation via banded MFMA + fused softmax ----------------
// output layout: wgt[b][k][y*W+x] bf16 (planar per tap, k = di*9+dj)
__global__ __launch_bounds__(128) void corr_mfma_k(
    const ushort* __restrict__ e, ushort* __restrict__ wgt) {
  __shared__ float S[2 * 16 * 91];
  const int wave = threadIdx.x >> 6, lane = threadIdx.x & 63;
  const int x0 = blockIdx.x * 16;
  const int y = blockIdx.y * 2 + wave;
  const int b = blockIdx.z;
  const int nl = lane & 15, kq = lane >> 4;
  const ushort* es = e + (size_t)b * EPL * 64;
  const ushort* ec = e + (size_t)(b + 4) * EPL * 64;
  size_t abase = ((size_t)(y + 4) * EPW + (size_t)(4 + x0 + nl)) * 64 + kq * 8;
  bf16x8 afr0 = *(const bf16x8*)(es + abase);
  bf16x8 afr1 = *(const bf16x8*)(es + abase + 32);
  float* Sw = &S[wave * 16 * 91];
  for (int di = 0; di < 9; di++) {
    const ushort* erow = ec + ((size_t)(y + di) * EPW + x0) * 64;
#pragma unroll
    for (int nh = 0; nh < 2; nh++) {
      f32x4 g = f32x4{0.f, 0.f, 0.f, 0.f};
      const ushort* bp = erow + (size_t)(nh * 16 + nl) * 64 + kq * 8;
      bf16x8 b0 = *(const bf16x8*)(bp);
      bf16x8 b1 = *(const bf16x8*)(bp + 32);
      g = __builtin_amdgcn_mfma_f32_16x16x32_bf16(afr0, b0, g, 0, 0, 0);
      g = __builtin_amdgcn_mfma_f32_16x16x32_bf16(afr1, b1, g, 0, 0, 0);
      int q = nh * 16 + nl;
#pragma unroll
      for (int r = 0; r < 4; r++) {
        int m = kq * 4 + r;
        int s = q - m;
        if (s >= 0 && s <= 8) Sw[m * 91 + di * 9 + s] = g[r];
      }
    }
  }
  int px = lane >> 2, lg = lane & 3;
  float* Sp = &Sw[px * 91];
  float mx = -1e30f;
  for (int k = lg; k < 81; k += 4) mx = fmaxf(mx, Sp[k]);
  mx = fmaxf(mx, __shfl_xor(mx, 1));
  mx = fmaxf(mx, __shfl_xor(mx, 2));
  float sum = 0.f;
  for (int k = lg; k < 81; k += 4) {
    float t = expf(Sp[k] - mx);
    Sp[k] = t;
    sum += t;
  }
  sum += __shfl_xor(sum, 1);
  sum += __shfl_xor(sum, 2);
  float rinv = 1.f / sum;
  if (x0 + px < W) {
    ushort* wp = wgt + (size_t)b * 81 * HW + (size_t)y * W + x0 + px;
    for (int k = lg; k < 81; k += 4) wp[(size_t)k * HW] = f2bf(Sp[k] * rinv);
  }
}

// ---------------- align v2: wave-distinct sliding-window gather ----------------
// out[c][y][x] = sum_{di,dj} w[y][x][di*9+dj] * fs[c][y+di-4][x+dj-4]
// Tile 16x x 16y. Block = 64 channels (grid z = b*2 + ch-half), 4 rounds x 16 ch.
// Wave: 64 lanes = 16 yy x 4 xq = ALL 64 px-quads (distinct!); wave -> channel.
// => every LDS read instr has 64 distinct, evenly-spread addresses:
//    Ws b64: slot(16B) = 2*yy + (xq>>1) covers all 32 slots exactly 2x (floor).
//    Fs b128: stride-24 rows, quarter-wave = 2 lanes per 16B-group (floor).
// R2 bug: cl=tid>>5 didn't enter Ws address -> half-wave duplicate b64 reads
// (and xq-pairs shared slots) -> 5.1e7 conflict cycles, LDS-pipe serialized.
// LDS: Ws[81][256] bf16 41.5K + Fs[16][24][24] f32 36K = 77.4K -> 2 blocks/CU.
__global__ __launch_bounds__(256, 2) void align_valu2_k(
    const ushort* __restrict__ wgt, const float* __restrict__ fs,
    float* __restrict__ out) {
  __shared__ ushort Ws[81 * 256];
  __shared__ float Fs[16 * 576];
  const int tid = threadIdx.x;
  // XCD swizzle: 1352 blocks; XCD x owns one full (b, ch-half) plane (169 blocks)
  int orig = blockIdx.x + 13 * blockIdx.y + 169 * blockIdx.z;
  int bz = orig & 7;
  int t = orig >> 3;
  int by = t / 13, bx = t % 13;
  const int b = bz >> 1, c00 = (bz & 1) * 64;
  const int x0 = bx * 16, y0 = by * 16;

  // stage Ws[81][256]: per-tap rows of the 16x16 px tile, uint4 chunks (b128 writes)
  {
    const ushort* wb = wgt + (size_t)b * 81 * HW;
    for (int i = tid; i < 81 * 32; i += 256) {
      int k = i >> 5, rw = (i & 31) >> 1, half = i & 1;
      int gy = y0 + rw;
      if (gy > H - 1) gy = H - 1;  // clamped rows feed only masked outputs
      const uint4* src =
          (const uint4*)(wb + (size_t)k * HW + (size_t)gy * W + x0 + half * 8);
      *(uint4*)&Ws[k * 256 + rw * 16 + half * 8] = *src;
    }
  }
  const int lane = tid & 63, wave = tid >> 6;
  const int yy = lane >> 2, xq = lane & 3;
  const int xb = x0 + xq * 4, yb = y0 + yy;
  const bool wr = (yb < H) && (xb + 3 < W);

  for (int r = 0; r < 4; ++r) {
    if (r) __syncthreads();
    // stage Fs: 16 ch x 24 rows x 24 cols f32 (halo 4); write addr == i (linear)
    {
      const float* fb = fs + ((size_t)b * 128 + c00 + r * 16) * HW;
      for (int i = tid; i < 16 * 576; i += 256) {
        int cc = i / 576, rem = i % 576;
        int row = rem / 24, col = rem % 24;
        int gy = y0 - 4 + row, gx = x0 - 4 + col;
        float v = 0.f;
        if (gy >= 0 && gy < H && gx >= 0 && gx < W)
          v = fb[(size_t)cc * HW + gy * W + gx];
        Fs[i] = v;
      }
    }
    __syncthreads();
    float acc[4][4];
#pragma unroll
    for (int j = 0; j < 4; j++)
#pragma unroll
      for (int p = 0; p < 4; p++) acc[j][p] = 0.f;
    for (int di = 0; di < 9; ++di) {
      float fr[4][12];
#pragma unroll
      for (int j = 0; j < 4; ++j) {
        const float4* fp =
            (const float4*)&Fs[(wave * 4 + j) * 576 + (yy + di) * 24 + xq * 4];
        float4 f0 = fp[0], f1 = fp[1], f2 = fp[2];
        fr[j][0] = f0.x; fr[j][1] = f0.y; fr[j][2] = f0.z; fr[j][3] = f0.w;
        fr[j][4] = f1.x; fr[j][5] = f1.y; fr[j][6] = f1.z; fr[j][7] = f1.w;
        fr[j][8] = f2.x; fr[j][9] = f2.y; fr[j][10] = f2.z; fr[j][11] = f2.w;
      }
#pragma unroll
      for (int dj = 0; dj < 9; ++dj) {
        uint2 wv = *(const uint2*)&Ws[(di * 9 + dj) * 256 + yy * 16 + xq * 4];
        float w0 = __uint_as_float(wv.x << 16);
        float w1 = __uint_as_float(wv.x & 0xffff0000u);
        float w2 = __uint_as_float(wv.y << 16);
        float w3 = __uint_as_float(wv.y & 0xffff0000u);
#pragma unroll
        for (int j = 0; j < 4; ++j) {
          acc[j][0] += w0 * fr[j][dj + 0];
          acc[j][1] += w1 * fr[j][dj + 1];
          acc[j][2] += w2 * fr[j][dj + 2];
          acc[j][3] += w3 * fr[j][dj + 3];
        }
      }
    }
    if (wr) {
#pragma unroll
      for (int j = 0; j < 4; ++j) {
        int c = c00 + r * 16 + wave * 4 + j;
        *(float4*)&out[((size_t)b * 128 + c) * HW + (size_t)yb * W + xb] =
            float4{acc[j][0], acc[j][1], acc[j][2], acc[j][3]};
      }
    }
  }
}

// ---------------- ag3 conv1x1 (32->1) + relu + 2-way softmax + blend ----------------
__global__ __launch_bounds__(256) void final_k(
    const float* __restrict__ a2, const float* __restrict__ w3,
    const float* __restrict__ b3, const float* __restrict__ alignb,
    const float* __restrict__ fcur, float* __restrict__ out) {
  int p = blockIdx.x * 256 + threadIdx.x;
  int bb = p / HW, pix = p % HW;
  const float* aS = a2 + (size_t)bb * 32 * HW + pix;
  const float* aC = a2 + (size_t)(bb + Bz) * 32 * HW + pix;
  float s0 = b3[0], s1 = b3[0];
#pragma unroll
  for (int c = 0; c < 32; c++) {
    float wv = w3[c];
    s0 += wv * aS[(size_t)c * HW];
    s1 += wv * aC[(size_t)c * HW];
  }
  s0 = fmaxf(s0, 0.f);
  s1 = fmaxf(s1, 0.f);
  float m = fmaxf(s0, s1);
  float e0 = expf(s0 - m), e1 = expf(s1 - m);
  float inv = 1.f / (e0 + e1);
  float p0 = e0 * inv, p1 = e1 * inv;
  const float* al = alignb + (size_t)bb * 128 * HW + pix;
  const float* fc = fcur + (size_t)bb * 128 * HW + pix;
  float* o = out + (size_t)bb * 128 * HW + pix;
#pragma unroll 4
  for (int c = 0; c < 128; c++)
    o[(size_t)c * HW] = p0 * al[(size_t)c * HW] + p1 * fc[(size_t)c * HW];
}

extern "C" void kernel_launch(void* const* d_in, const int* in_sizes, int n_in,
                              void* d_out, int out_size, void* d_ws, size_t ws_size,
                              hipStream_t stream) {
  const float* fsel = (const float*)d_in[0];
  const float* fcur = (const float*)d_in[1];
  const float* ec1_w = (const float*)d_in[2];
  const float* ec1_b = (const float*)d_in[3];
  const float* ec2_w = (const float*)d_in[4];
  const float* ec2_b = (const float*)d_in[5];
  const float* ag1_w = (const float*)d_in[6];
  const float* ag1_b = (const float*)d_in[7];
  const float* ag2_w = (const float*)d_in[8];
  const float* ag2_b = (const float*)d_in[9];
  const float* ag3_w = (const float*)d_in[10];
  const float* ag3_b = (const float*)d_in[11];

  char* ws = (char*)d_ws;
  size_t off = 4096;
  ushort* padbuf = (ushort*)(ws + off);
  size_t padbuf_bytes = (size_t)8 * PPLANE * 64 * 2;
  off += padbuf_bytes;
  ushort* epad = (ushort*)(ws + off);
  size_t epad_bytes = (size_t)8 * EPL * 64 * 2;
  off += epad_bytes + 4096;
  ushort* wgtb = (ushort*)(ws + off);
  off += (size_t)4 * 81 * HW * 2 + 4096;
  float* alignb = (float*)(ws + off);
  off += (size_t)4 * 128 * HW * 4;
  ushort* wb1 = (ushort*)(ws + off);
  off += 9 * 64 * 64 * 2;
  ushort* wb2 = (ushort*)(ws + off);
  off += 9 * 32 * 64 * 2;
  float* a2 = (float*)epad;
  float* outp = (float*)d_out;

  dim3 blk(256);
  const int MTILES = (200 * PW + 255) / 256; // 163

  wxform_k<<<(9 * 64 * 64 + 255) / 256, blk, 0, stream>>>(ec2_w, wb1, 64);
  wxform_k<<<(9 * 32 * 64 + 255) / 256, blk, 0, stream>>>(ag2_w, wb2, 32);
  {
    int nz = (int)((padbuf_bytes + epad_bytes) / 16);
    zero_k<<<(nz + 255) / 256, blk, 0, stream>>>((uint4*)padbuf, nz);
  }
  conv1x1_nhwc_k<128><<<1250, blk, 0, stream>>>(fsel, fcur, ec1_w, ec1_b, padbuf);
  conv3x3_mfma_k<64, true><<<dim3(MTILES, 8), blk, 0, stream>>>(
      padbuf, wb1, ec2_b, nullptr, epad);
  corr_mfma_k<<<dim3(13, 100, 4), dim3(128), 0, stream>>>(epad, wgtb);
  align_valu2_k<<<dim3(13, 13, 8), blk, 0, stream>>>(wgtb, fsel, alignb);
  conv1x1_nhwc_k<128><<<1250, blk, 0, stream>>>(alignb, fcur, ag1_w, ag1_b, padbuf);
  conv3x3_mfma_k<32, false><<<dim3(MTILES, 8), blk, 0, stream>>>(
      padbuf, wb2, ag2_b, a2, nullptr);
  final_k<<<625, blk, 0, stream>>>(a2, ag3_w, ag3_b, alignb, fcur, outp);
}

// Round 6
// 874.453 us; speedup vs baseline: 1.2373x; 1.1271x over previous
//
#include <hip/hip_runtime.h>

namespace {
constexpr int H = 200, W = 200, HW = H * W;
constexpr int Bz = 4;
constexpr int PW = 208, PH = 202, PPLANE = PW * PH; // conv1x1 pad geometry (halo 1)
constexpr int EPW = 208, EPH = 208, EPL = EPW * EPH; // e-pad geometry (halo 4)
}

typedef __attribute__((ext_vector_type(8))) short bf16x8;
typedef __attribute__((ext_vector_type(4))) float f32x4;

__device__ inline ushort f2bf(float f) {
  unsigned u = __float_as_uint(f);
  u += 0x7fffu + ((u >> 16) & 1u);
  return (ushort)(u >> 16);
}

// ---------------- zero fill ----------------
__global__ __launch_bounds__(256) void zero_k(uint4* __restrict__ p, int n) {
  int i = blockIdx.x * 256 + threadIdx.x;
  if (i < n) p[i] = uint4{0u, 0u, 0u, 0u};
}

// ---------------- weight transform: OIHW fp32 -> [tap][co][ci] bf16 ----------------
__global__ __launch_bounds__(256) void wxform_k(const float* __restrict__ w,
                                                ushort* __restrict__ wb, int cout) {
  int i = blockIdx.x * 256 + threadIdx.x;
  int tot = cout * 64 * 9;
  if (i >= tot) return;
  int co = i / (64 * 9);
  int r = i % (64 * 9);
  int ci = r / 9, tap = r % 9;
  wb[(tap * cout + co) * 64 + ci] = f2bf(w[i]);
}

// ---------------- conv1x1 + bias + relu -> bf16 NHWC padded (halo 1) ----------------
template <int CIN>
__global__ __launch_bounds__(256) void conv1x1_nhwc_k(
    const float* __restrict__ srcA, const float* __restrict__ srcB,
    const float* __restrict__ w, const float* __restrict__ bias,
    ushort* __restrict__ out) {
  __shared__ float wt[CIN * 64];
  for (int i = threadIdx.x; i < CIN * 64; i += 256) {
    int ci = i >> 6, co = i & 63;
    wt[i] = w[co * CIN + ci];
  }
  __syncthreads();
  int p = blockIdx.x * 256 + threadIdx.x;
  int bb = p / HW, pix = p % HW;
  const float* src =
      (bb < Bz ? srcA + (size_t)bb * CIN * HW : srcB + (size_t)(bb - Bz) * CIN * HW) + pix;
  float acc[64];
#pragma unroll
  for (int co = 0; co < 64; co++) acc[co] = bias[co];
  for (int ci = 0; ci < CIN; ci++) {
    float x = src[(size_t)ci * HW];
    const float4* w4 = (const float4*)&wt[ci * 64];
#pragma unroll
    for (int q = 0; q < 16; q++) {
      float4 wv = w4[q];
      acc[4 * q + 0] += x * wv.x;
      acc[4 * q + 1] += x * wv.y;
      acc[4 * q + 2] += x * wv.z;
      acc[4 * q + 3] += x * wv.w;
    }
  }
  int y = pix / W, x = pix % W;
  ushort* o = out + ((size_t)bb * PPLANE + (size_t)(y + 1) * PW + (x + 1)) * 64;
  uint4* o4 = (uint4*)o;
#pragma unroll
  for (int g = 0; g < 8; g++) {
    unsigned u0 = (unsigned)f2bf(fmaxf(acc[8 * g + 0], 0.f)) |
                  ((unsigned)f2bf(fmaxf(acc[8 * g + 1], 0.f)) << 16);
    unsigned u1 = (unsigned)f2bf(fmaxf(acc[8 * g + 2], 0.f)) |
                  ((unsigned)f2bf(fmaxf(acc[8 * g + 3], 0.f)) << 16);
    unsigned u2 = (unsigned)f2bf(fmaxf(acc[8 * g + 4], 0.f)) |
                  ((unsigned)f2bf(fmaxf(acc[8 * g + 5], 0.f)) << 16);
    unsigned u3 = (unsigned)f2bf(fmaxf(acc[8 * g + 6], 0.f)) |
                  ((unsigned)f2bf(fmaxf(acc[8 * g + 7], 0.f)) << 16);
    o4[g] = uint4{u0, u1, u2, u3};
  }
}

// ---------------- conv3x3 via bf16 MFMA implicit GEMM ----------------
template <int COUT, bool NHWC>
__global__ __launch_bounds__(256) void conv3x3_mfma_k(
    const ushort* __restrict__ in, const ushort* __restrict__ wb,
    const float* __restrict__ bias, float* __restrict__ outf,
    ushort* __restrict__ outh) {
  constexpr int NF = COUT / 16;
  __shared__ ushort As[272 * 72];
  __shared__ ushort Bs[3 * COUT * 64];
  const int tile = blockIdx.x, img = blockIdx.y;
  const int pp0 = PW + tile * 256;
  const int tid = threadIdx.x, wave = tid >> 6, lane = tid & 63;
  const int lm = lane & 15, lq = lane >> 4;
  const ushort* inb = in + (size_t)img * PPLANE * 64;

  f32x4 acc[4][NF];
#pragma unroll
  for (int mf = 0; mf < 4; mf++)
#pragma unroll
    for (int nf = 0; nf < NF; nf++) acc[mf][nf] = f32x4{0.f, 0.f, 0.f, 0.f};

  for (int dy = 0; dy < 3; dy++) {
    __syncthreads();
    long abase = ((long)pp0 + (long)(dy - 1) * PW - 8) * 64;
    for (int i = tid; i < 272 * 8; i += 256) {
      int m = i >> 3, kseg = i & 7;
      uint4 v = *(const uint4*)(inb + abase + (long)m * 64 + kseg * 8);
      *(uint4*)&As[m * 72 + kseg * 8] = v;
    }
    for (int i = tid; i < 3 * COUT * 8; i += 256) {
      int dx = i / (COUT * 8);
      int r = i % (COUT * 8);
      int co = r >> 3, kseg = r & 7;
      uint4 v = *(const uint4*)(wb + (((size_t)(dy * 3 + dx) * COUT + co) << 6) + kseg * 8);
      *(uint4*)&Bs[(dx * COUT + co) * 64 + ((kseg ^ (co & 7)) * 8)] = v;
    }
    __syncthreads();
#pragma unroll
    for (int dx = 0; dx < 3; dx++) {
#pragma unroll
      for (int kc = 0; kc < 2; kc++) {
        bf16x8 bfr[NF];
#pragma unroll
        for (int nf = 0; nf < NF; nf++) {
          int n = nf * 16 + lm;
          int kb = kc * 4 + lq;
          bfr[nf] = *(const bf16x8*)&Bs[(dx * COUT + n) * 64 + ((kb ^ (n & 7)) * 8)];
        }
#pragma unroll
        for (int mf = 0; mf < 4; mf++) {
          int mo = (wave * 4 + mf) * 16 + lm;
          bf16x8 afr = *(const bf16x8*)&As[(mo + dx + 7) * 72 + kc * 32 + lq * 8];
#pragma unroll
          for (int nf = 0; nf < NF; nf++)
            acc[mf][nf] = __builtin_amdgcn_mfma_f32_16x16x32_bf16(afr, bfr[nf],
                                                                  acc[mf][nf], 0, 0, 0);
        }
      }
    }
  }
  float bv[NF];
#pragma unroll
  for (int nf = 0; nf < NF; nf++) bv[nf] = bias[nf * 16 + lm];
#pragma unroll
  for (int mf = 0; mf < 4; mf++) {
#pragma unroll
    for (int nf = 0; nf < NF; nf++) {
      int co = nf * 16 + lm;
#pragma unroll
      for (int r = 0; r < 4; r++) {
        int mo = pp0 + (wave * 4 + mf) * 16 + lq * 4 + r;
        int py = mo / PW, px = mo % PW;
        if (py >= 1 && py <= H && px >= 1 && px <= W) {
          float v = fmaxf(acc[mf][nf][r] + bv[nf], 0.f);
          if (NHWC) {
            ushort* eo = outh + (size_t)img * EPL * 64;
            eo[(((size_t)(py + 3)) * EPW + (px + 3)) * 64 + co] = f2bf(v);
          } else {
            outf[((size_t)img * COUT + co) * HW + (py - 1) * W + (px - 1)] = v;
          }
        }
      }
    }
  }
}

// ---------------- correlation via banded MFMA + fused softmax ----------------
// output layout: wgt[b][k][y*W+x] bf16 (planar per tap, k = di*9+dj)
__global__ __launch_bounds__(128) void corr_mfma_k(
    const ushort* __restrict__ e, ushort* __restrict__ wgt) {
  __shared__ float S[2 * 16 * 91];
  const int wave = threadIdx.x >> 6, lane = threadIdx.x & 63;
  const int x0 = blockIdx.x * 16;
  const int y = blockIdx.y * 2 + wave;
  const int b = blockIdx.z;
  const int nl = lane & 15, kq = lane >> 4;
  const ushort* es = e + (size_t)b * EPL * 64;
  const ushort* ec = e + (size_t)(b + 4) * EPL * 64;
  size_t abase = ((size_t)(y + 4) * EPW + (size_t)(4 + x0 + nl)) * 64 + kq * 8;
  bf16x8 afr0 = *(const bf16x8*)(es + abase);
  bf16x8 afr1 = *(const bf16x8*)(es + abase + 32);
  float* Sw = &S[wave * 16 * 91];
  for (int di = 0; di < 9; di++) {
    const ushort* erow = ec + ((size_t)(y + di) * EPW + x0) * 64;
#pragma unroll
    for (int nh = 0; nh < 2; nh++) {
      f32x4 g = f32x4{0.f, 0.f, 0.f, 0.f};
      const ushort* bp = erow + (size_t)(nh * 16 + nl) * 64 + kq * 8;
      bf16x8 b0 = *(const bf16x8*)(bp);
      bf16x8 b1 = *(const bf16x8*)(bp + 32);
      g = __builtin_amdgcn_mfma_f32_16x16x32_bf16(afr0, b0, g, 0, 0, 0);
      g = __builtin_amdgcn_mfma_f32_16x16x32_bf16(afr1, b1, g, 0, 0, 0);
      int q = nh * 16 + nl;
#pragma unroll
      for (int r = 0; r < 4; r++) {
        int m = kq * 4 + r;
        int s = q - m;
        if (s >= 0 && s <= 8) Sw[m * 91 + di * 9 + s] = g[r];
      }
    }
  }
  int px = lane >> 2, lg = lane & 3;
  float* Sp = &Sw[px * 91];
  float mx = -1e30f;
  for (int k = lg; k < 81; k += 4) mx = fmaxf(mx, Sp[k]);
  mx = fmaxf(mx, __shfl_xor(mx, 1));
  mx = fmaxf(mx, __shfl_xor(mx, 2));
  float sum = 0.f;
  for (int k = lg; k < 81; k += 4) {
    float t = expf(Sp[k] - mx);
    Sp[k] = t;
    sum += t;
  }
  sum += __shfl_xor(sum, 1);
  sum += __shfl_xor(sum, 2);
  float rinv = 1.f / sum;
  if (x0 + px < W) {
    ushort* wp = wgt + (size_t)b * 81 * HW + (size_t)y * W + x0 + px;
    for (int k = lg; k < 81; k += 4) wp[(size_t)k * HW] = f2bf(Sp[k] * rinv);
  }
}

// ---------------- align v3b: banded MFMA, band scattered into LDS ----------------
// Per output row y, fixed di:  out[x][c] += sum_dj w[x][di*9+dj]*fs[c][y+di-4][x+dj-4]
// = banded GEMM: M=16 px, N=16 ch, K=32 x-window; A[y][m][m+dj]=w built once per
// di in LDS and shared by all waves. 16 ch/block (vs R4's 32): LDS = 51200 B --
// R4's 80KB x 2/CU hit the 160KiB pool EXACTLY (only resource-boundary diff vs
// every passing kernel); 51200x3 = 150KB has slack, 3 blocks/CU, 12 waves/CU.
// Stride 40 ush = 80B: 16B-aligned b128, quarter-wave = 2 lanes/4-bank grp (floor).
// Fragment convention identical to conv3x3_mfma_k.
__global__ __launch_bounds__(256, 3) void align_mfma2_k(
    const ushort* __restrict__ wgt, const float* __restrict__ fs,
    float* __restrict__ out) {
  __shared__ alignas(16) ushort As2[16 * 16 * 40];  // 20480 B
  __shared__ alignas(16) ushort Fs2[24 * 16 * 40];  // 30720 B
  const int tid = threadIdx.x;
  // 5408 blocks = 8 planes x 676. Plane p = b*2+h (one XCD per (b, ch-half));
  // rank = tile*4 + cgi: 4 consecutive blocks share one wgt tile (L2 reuse).
  int bid = blockIdx.x;
  int p = bid & 7;
  int rank = bid >> 3;               // 0..675
  const int b = p >> 1, h = p & 1;
  const int cgi = rank & 3;
  int tile = rank >> 2;              // 0..168
  const int ty = tile / 13, tx = tile % 13;
  const int x0 = tx * 16, y0 = ty * 16;
  const int c0 = (h * 4 + cgi) * 16;

  // zero band matrix once (each di's scatter overwrites the same slots)
  for (int i = tid; i < 1280; i += 256) *(uint4*)&As2[i * 8] = uint4{0u, 0u, 0u, 0u};

  // prefetch wgt row for di=0 (latency hides under F staging)
  const int srow = tid >> 4, sm = tid & 15;
  const bool sval = (y0 + srow < H) && (x0 + sm < W);
  const ushort* wrow =
      wgt + (size_t)b * 81 * HW + (size_t)(y0 + srow) * W + (x0 + sm);
  ushort wv[9];
  if (sval) {
#pragma unroll
    for (int dj = 0; dj < 9; dj++) wv[dj] = wrow[(size_t)dj * HW];
  }

  // stage F: rows y0-4..y0+19, k-window x0-4..x0+19 (k<24; 24..31 zeroed)
  {
    const float* fb = fs + ((size_t)b * 128 + c0) * HW;
    for (int i = tid; i < 24 * 16 * 32; i += 256) {
      int k = i & 31;
      int c = (i >> 5) & 15;
      int rf = i >> 9;
      int gy = y0 - 4 + rf, gx = x0 - 4 + k;
      float v = 0.f;
      if (k < 24 && gy >= 0 && gy < H && gx >= 0 && gx < W)
        v = fb[(size_t)c * HW + (size_t)gy * W + gx];
      Fs2[(rf * 16 + c) * 40 + k] = f2bf(v);
    }
  }
  __syncthreads();

  const int lane = tid & 63, wave = tid >> 6;
  const int nl = lane & 15, kq = lane >> 4;
  f32x4 acc[4];
#pragma unroll
  for (int rr = 0; rr < 4; rr++) acc[rr] = f32x4{0.f, 0.f, 0.f, 0.f};

  for (int di = 0; di < 9; ++di) {
    if (sval) {
#pragma unroll
      for (int dj = 0; dj < 9; dj++)
        As2[(srow * 16 + sm) * 40 + sm + dj] = wv[dj];
    }
    if (di < 8 && sval) {
      const ushort* wn = wrow + (size_t)((di + 1) * 9) * HW;
#pragma unroll
      for (int dj = 0; dj < 9; dj++) wv[dj] = wn[(size_t)dj * HW];
    }
    __syncthreads();
#pragma unroll
    for (int rr = 0; rr < 4; ++rr) {
      int row = wave * 4 + rr;
      bf16x8 af = *(const bf16x8*)&As2[(row * 16 + nl) * 40 + kq * 8];
      int rf = row + di;
      bf16x8 bf = *(const bf16x8*)&Fs2[(rf * 16 + nl) * 40 + kq * 8];
      acc[rr] = __builtin_amdgcn_mfma_f32_16x16x32_bf16(af, bf, acc[rr], 0, 0, 0);
    }
    __syncthreads();
  }

  // store: C row = kq*4+r -> x = x0+kq*4+r; col = nl -> channel
  const int xs = x0 + kq * 4;
  if (xs + 3 < W) {
    int c = c0 + nl;
#pragma unroll
    for (int rr = 0; rr < 4; ++rr) {
      int y = y0 + wave * 4 + rr;
      if (y < H) {
        *(float4*)&out[((size_t)b * 128 + c) * HW + (size_t)y * W + xs] =
            float4{acc[rr][0], acc[rr][1], acc[rr][2], acc[rr][3]};
      }
    }
  }
}

// ---------------- ag3 conv1x1 (32->1) + relu + 2-way softmax + blend ----------------
__global__ __launch_bounds__(256) void final_k(
    const float* __restrict__ a2, const float* __restrict__ w3,
    const float* __restrict__ b3, const float* __restrict__ alignb,
    const float* __restrict__ fcur, float* __restrict__ out) {
  int p = blockIdx.x * 256 + threadIdx.x;
  int bb = p / HW, pix = p % HW;
  const float* aS = a2 + (size_t)bb * 32 * HW + pix;
  const float* aC = a2 + (size_t)(bb + Bz) * 32 * HW + pix;
  float s0 = b3[0], s1 = b3[0];
#pragma unroll
  for (int c = 0; c < 32; c++) {
    float wv = w3[c];
    s0 += wv * aS[(size_t)c * HW];
    s1 += wv * aC[(size_t)c * HW];
  }
  s0 = fmaxf(s0, 0.f);
  s1 = fmaxf(s1, 0.f);
  float m = fmaxf(s0, s1);
  float e0 = expf(s0 - m), e1 = expf(s1 - m);
  float inv = 1.f / (e0 + e1);
  float p0 = e0 * inv, p1 = e1 * inv;
  const float* al = alignb + (size_t)bb * 128 * HW + pix;
  const float* fc = fcur + (size_t)bb * 128 * HW + pix;
  float* o = out + (size_t)bb * 128 * HW + pix;
#pragma unroll 4
  for (int c = 0; c < 128; c++)
    o[(size_t)c * HW] = p0 * al[(size_t)c * HW] + p1 * fc[(size_t)c * HW];
}

extern "C" void kernel_launch(void* const* d_in, const int* in_sizes, int n_in,
                              void* d_out, int out_size, void* d_ws, size_t ws_size,
                              hipStream_t stream) {
  const float* fsel = (const float*)d_in[0];
  const float* fcur = (const float*)d_in[1];
  const float* ec1_w = (const float*)d_in[2];
  const float* ec1_b = (const float*)d_in[3];
  const float* ec2_w = (const float*)d_in[4];
  const float* ec2_b = (const float*)d_in[5];
  const float* ag1_w = (const float*)d_in[6];
  const float* ag1_b = (const float*)d_in[7];
  const float* ag2_w = (const float*)d_in[8];
  const float* ag2_b = (const float*)d_in[9];
  const float* ag3_w = (const float*)d_in[10];
  const float* ag3_b = (const float*)d_in[11];

  char* ws = (char*)d_ws;
  size_t off = 4096;
  ushort* padbuf = (ushort*)(ws + off);
  size_t padbuf_bytes = (size_t)8 * PPLANE * 64 * 2;
  off += padbuf_bytes;
  ushort* epad = (ushort*)(ws + off);
  size_t epad_bytes = (size_t)8 * EPL * 64 * 2;
  off += epad_bytes + 4096;
  ushort* wgtb = (ushort*)(ws + off);
  off += (size_t)4 * 81 * HW * 2 + 4096;
  float* alignb = (float*)(ws + off);
  off += (size_t)4 * 128 * HW * 4;
  ushort* wb1 = (ushort*)(ws + off);
  off += 9 * 64 * 64 * 2;
  ushort* wb2 = (ushort*)(ws + off);
  off += 9 * 32 * 64 * 2;
  float* a2 = (float*)epad;
  float* outp = (float*)d_out;

  dim3 blk(256);
  const int MTILES = (200 * PW + 255) / 256; // 163

  wxform_k<<<(9 * 64 * 64 + 255) / 256, blk, 0, stream>>>(ec2_w, wb1, 64);
  wxform_k<<<(9 * 32 * 64 + 255) / 256, blk, 0, stream>>>(ag2_w, wb2, 32);
  {
    int nz = (int)((padbuf_bytes + epad_bytes) / 16);
    zero_k<<<(nz + 255) / 256, blk, 0, stream>>>((uint4*)padbuf, nz);
  }
  conv1x1_nhwc_k<128><<<1250, blk, 0, stream>>>(fsel, fcur, ec1_w, ec1_b, padbuf);
  conv3x3_mfma_k<64, true><<<dim3(MTILES, 8), blk, 0, stream>>>(
      padbuf, wb1, ec2_b, nullptr, epad);
  corr_mfma_k<<<dim3(13, 100, 4), dim3(128), 0, stream>>>(epad, wgtb);
  align_mfma2_k<<<5408, blk, 0, stream>>>(wgtb, fsel, alignb);
  conv1x1_nhwc_k<128><<<1250, blk, 0, stream>>>(alignb, fcur, ag1_w, ag1_b, padbuf);
  conv3x3_mfma_k<32, false><<<dim3(MTILES, 8), blk, 0, stream>>>(
      padbuf, wb2, ag2_b, a2, nullptr);
  final_k<<<625, blk, 0, stream>>>(a2, ag3_w, ag3_b, alignb, fcur, outp);
}

// Round 7
// 815.083 us; speedup vs baseline: 1.3275x; 1.0728x over previous
//
#include <hip/hip_runtime.h>

namespace {
constexpr int H = 200, W = 200, HW = H * W;
constexpr int Bz = 4;
constexpr int PW = 208, PH = 202, PPLANE = PW * PH; // conv1x1 pad geometry (halo 1)
constexpr int EPW = 208, EPH = 208, EPL = EPW * EPH; // e-pad geometry (halo 4)
constexpr int WST = 96; // per-pixel wgt row: tap (di,dj) at di*10+dj (4B-aligned dice)
}

typedef __attribute__((ext_vector_type(8))) short bf16x8;
typedef __attribute__((ext_vector_type(4))) float f32x4;

__device__ inline ushort f2bf(float f) {
  unsigned u = __float_as_uint(f);
  u += 0x7fffu + ((u >> 16) & 1u);
  return (ushort)(u >> 16);
}

// ---------------- zero fill ----------------
__global__ __launch_bounds__(256) void zero_k(uint4* __restrict__ p, int n) {
  int i = blockIdx.x * 256 + threadIdx.x;
  if (i < n) p[i] = uint4{0u, 0u, 0u, 0u};
}

// ---------------- weight transform: OIHW fp32 -> [tap][co][ci] bf16 ----------------
__global__ __launch_bounds__(256) void wxform_k(const float* __restrict__ w,
                                                ushort* __restrict__ wb, int cout) {
  int i = blockIdx.x * 256 + threadIdx.x;
  int tot = cout * 64 * 9;
  if (i >= tot) return;
  int co = i / (64 * 9);
  int r = i % (64 * 9);
  int ci = r / 9, tap = r % 9;
  wb[(tap * cout + co) * 64 + ci] = f2bf(w[i]);
}

// ---------------- conv1x1 + bias + relu -> bf16 NHWC padded (halo 1) ----------------
template <int CIN>
__global__ __launch_bounds__(256) void conv1x1_nhwc_k(
    const float* __restrict__ srcA, const float* __restrict__ srcB,
    const float* __restrict__ w, const float* __restrict__ bias,
    ushort* __restrict__ out) {
  __shared__ float wt[CIN * 64];
  for (int i = threadIdx.x; i < CIN * 64; i += 256) {
    int ci = i >> 6, co = i & 63;
    wt[i] = w[co * CIN + ci];
  }
  __syncthreads();
  int p = blockIdx.x * 256 + threadIdx.x;
  int bb = p / HW, pix = p % HW;
  const float* src =
      (bb < Bz ? srcA + (size_t)bb * CIN * HW : srcB + (size_t)(bb - Bz) * CIN * HW) + pix;
  float acc[64];
#pragma unroll
  for (int co = 0; co < 64; co++) acc[co] = bias[co];
  for (int ci = 0; ci < CIN; ci++) {
    float x = src[(size_t)ci * HW];
    const float4* w4 = (const float4*)&wt[ci * 64];
#pragma unroll
    for (int q = 0; q < 16; q++) {
      float4 wv = w4[q];
      acc[4 * q + 0] += x * wv.x;
      acc[4 * q + 1] += x * wv.y;
      acc[4 * q + 2] += x * wv.z;
      acc[4 * q + 3] += x * wv.w;
    }
  }
  int y = pix / W, x = pix % W;
  ushort* o = out + ((size_t)bb * PPLANE + (size_t)(y + 1) * PW + (x + 1)) * 64;
  uint4* o4 = (uint4*)o;
#pragma unroll
  for (int g = 0; g < 8; g++) {
    unsigned u0 = (unsigned)f2bf(fmaxf(acc[8 * g + 0], 0.f)) |
                  ((unsigned)f2bf(fmaxf(acc[8 * g + 1], 0.f)) << 16);
    unsigned u1 = (unsigned)f2bf(fmaxf(acc[8 * g + 2], 0.f)) |
                  ((unsigned)f2bf(fmaxf(acc[8 * g + 3], 0.f)) << 16);
    unsigned u2 = (unsigned)f2bf(fmaxf(acc[8 * g + 4], 0.f)) |
                  ((unsigned)f2bf(fmaxf(acc[8 * g + 5], 0.f)) << 16);
    unsigned u3 = (unsigned)f2bf(fmaxf(acc[8 * g + 6], 0.f)) |
                  ((unsigned)f2bf(fmaxf(acc[8 * g + 7], 0.f)) << 16);
    o4[g] = uint4{u0, u1, u2, u3};
  }
}

// ---------------- conv3x3 via bf16 MFMA implicit GEMM ----------------
template <int COUT, bool NHWC>
__global__ __launch_bounds__(256) void conv3x3_mfma_k(
    const ushort* __restrict__ in, const ushort* __restrict__ wb,
    const float* __restrict__ bias, float* __restrict__ outf,
    ushort* __restrict__ outh) {
  constexpr int NF = COUT / 16;
  __shared__ ushort As[272 * 72];
  __shared__ ushort Bs[3 * COUT * 64];
  const int tile = blockIdx.x, img = blockIdx.y;
  const int pp0 = PW + tile * 256;
  const int tid = threadIdx.x, wave = tid >> 6, lane = tid & 63;
  const int lm = lane & 15, lq = lane >> 4;
  const ushort* inb = in + (size_t)img * PPLANE * 64;

  f32x4 acc[4][NF];
#pragma unroll
  for (int mf = 0; mf < 4; mf++)
#pragma unroll
    for (int nf = 0; nf < NF; nf++) acc[mf][nf] = f32x4{0.f, 0.f, 0.f, 0.f};

  for (int dy = 0; dy < 3; dy++) {
    __syncthreads();
    long abase = ((long)pp0 + (long)(dy - 1) * PW - 8) * 64;
    for (int i = tid; i < 272 * 8; i += 256) {
      int m = i >> 3, kseg = i & 7;
      uint4 v = *(const uint4*)(inb + abase + (long)m * 64 + kseg * 8);
      *(uint4*)&As[m * 72 + kseg * 8] = v;
    }
    for (int i = tid; i < 3 * COUT * 8; i += 256) {
      int dx = i / (COUT * 8);
      int r = i % (COUT * 8);
      int co = r >> 3, kseg = r & 7;
      uint4 v = *(const uint4*)(wb + (((size_t)(dy * 3 + dx) * COUT + co) << 6) + kseg * 8);
      *(uint4*)&Bs[(dx * COUT + co) * 64 + ((kseg ^ (co & 7)) * 8)] = v;
    }
    __syncthreads();
#pragma unroll
    for (int dx = 0; dx < 3; dx++) {
#pragma unroll
      for (int kc = 0; kc < 2; kc++) {
        bf16x8 bfr[NF];
#pragma unroll
        for (int nf = 0; nf < NF; nf++) {
          int n = nf * 16 + lm;
          int kb = kc * 4 + lq;
          bfr[nf] = *(const bf16x8*)&Bs[(dx * COUT + n) * 64 + ((kb ^ (n & 7)) * 8)];
        }
#pragma unroll
        for (int mf = 0; mf < 4; mf++) {
          int mo = (wave * 4 + mf) * 16 + lm;
          bf16x8 afr = *(const bf16x8*)&As[(mo + dx + 7) * 72 + kc * 32 + lq * 8];
#pragma unroll
          for (int nf = 0; nf < NF; nf++)
            acc[mf][nf] = __builtin_amdgcn_mfma_f32_16x16x32_bf16(afr, bfr[nf],
                                                                  acc[mf][nf], 0, 0, 0);
        }
      }
    }
  }
  float bv[NF];
#pragma unroll
  for (int nf = 0; nf < NF; nf++) bv[nf] = bias[nf * 16 + lm];
#pragma unroll
  for (int mf = 0; mf < 4; mf++) {
#pragma unroll
    for (int nf = 0; nf < NF; nf++) {
      int co = nf * 16 + lm;
#pragma unroll
      for (int r = 0; r < 4; r++) {
        int mo = pp0 + (wave * 4 + mf) * 16 + lq * 4 + r;
        int py = mo / PW, px = mo % PW;
        if (py >= 1 && py <= H && px >= 1 && px <= W) {
          float v = fmaxf(acc[mf][nf][r] + bv[nf], 0.f);
          if (NHWC) {
            ushort* eo = outh + (size_t)img * EPL * 64;
            eo[(((size_t)(py + 3)) * EPW + (px + 3)) * 64 + co] = f2bf(v);
          } else {
            outf[((size_t)img * COUT + co) * HW + (py - 1) * W + (px - 1)] = v;
          }
        }
      }
    }
  }
}

// ---------------- correlation via banded MFMA + fused softmax ----------------
// output layout: per-pixel wgt[pix][WST=96], tap (di,dj) at index di*10+dj
// (4B-aligned per-di segments so align can fetch 9 taps as dword loads)
__global__ __launch_bounds__(128) void corr_mfma_k(
    const ushort* __restrict__ e, ushort* __restrict__ wgt) {
  __shared__ float S[2 * 16 * 91];
  const int wave = threadIdx.x >> 6, lane = threadIdx.x & 63;
  const int x0 = blockIdx.x * 16;
  const int y = blockIdx.y * 2 + wave;
  const int b = blockIdx.z;
  const int nl = lane & 15, kq = lane >> 4;
  const ushort* es = e + (size_t)b * EPL * 64;
  const ushort* ec = e + (size_t)(b + 4) * EPL * 64;
  size_t abase = ((size_t)(y + 4) * EPW + (size_t)(4 + x0 + nl)) * 64 + kq * 8;
  bf16x8 afr0 = *(const bf16x8*)(es + abase);
  bf16x8 afr1 = *(const bf16x8*)(es + abase + 32);
  float* Sw = &S[wave * 16 * 91];
  for (int di = 0; di < 9; di++) {
    const ushort* erow = ec + ((size_t)(y + di) * EPW + x0) * 64;
#pragma unroll
    for (int nh = 0; nh < 2; nh++) {
      f32x4 g = f32x4{0.f, 0.f, 0.f, 0.f};
      const ushort* bp = erow + (size_t)(nh * 16 + nl) * 64 + kq * 8;
      bf16x8 b0 = *(const bf16x8*)(bp);
      bf16x8 b1 = *(const bf16x8*)(bp + 32);
      g = __builtin_amdgcn_mfma_f32_16x16x32_bf16(afr0, b0, g, 0, 0, 0);
      g = __builtin_amdgcn_mfma_f32_16x16x32_bf16(afr1, b1, g, 0, 0, 0);
      int q = nh * 16 + nl;
#pragma unroll
      for (int r = 0; r < 4; r++) {
        int m = kq * 4 + r;
        int s = q - m;
        if (s >= 0 && s <= 8) Sw[m * 91 + di * 9 + s] = g[r];
      }
    }
  }
  int px = lane >> 2, lg = lane & 3;
  float* Sp = &Sw[px * 91];
  float mx = -1e30f;
  for (int k = lg; k < 81; k += 4) mx = fmaxf(mx, Sp[k]);
  mx = fmaxf(mx, __shfl_xor(mx, 1));
  mx = fmaxf(mx, __shfl_xor(mx, 2));
  float sum = 0.f;
  for (int k = lg; k < 81; k += 4) {
    float t = expf(Sp[k] - mx);
    Sp[k] = t;
    sum += t;
  }
  sum += __shfl_xor(sum, 1);
  sum += __shfl_xor(sum, 2);
  float rinv = 1.f / sum;
  if (x0 + px < W) {
    ushort* wp = wgt + ((size_t)b * 40000 + (size_t)y * W + x0 + px) * WST;
    for (int k = lg; k < 81; k += 4) wp[(k / 9) * 10 + k % 9] = f2bf(Sp[k] * rinv);
  }
}

// ---------------- align v4: banded MFMA, double-buffered band, 1 barrier/di ------
// Same algebra as R6 (verified): per y-row, fixed di, out[x][c] += band-GEMM
// M=16 px, N=16 ch, K=32 x-window, A[m][m+dj]=w scattered in LDS.
// R6 post-mortem: all pipes <31% -> latency-bound on (a) 18 barriers/block,
// (b) 48 scalar f32 Fs loads @68 VGPR, (c) 81 wgt loads on 81 DIFFERENT lines.
// Fixes: (a) As2[2] ping-pong: scatter(di+1) overlaps MFMA(di), 1 barrier/di;
// (b) interior tiles stage Fs via 6x float4 + 4x uint4 ds_write per row;
// (c) per-pixel wgt rows (WST=96): 9 taps = 4 dword + 1 ushort, one cache line.
// LDS 2*20480 + 30720 = 71680 B -> 2 blocks/CU.
__global__ __launch_bounds__(256, 2) void align_mfma3_k(
    const ushort* __restrict__ wgt, const float* __restrict__ fs,
    float* __restrict__ out) {
  __shared__ alignas(16) ushort As2[2 * 16 * 16 * 40];  // 2 x 20480 B
  __shared__ alignas(16) ushort Fs2[24 * 16 * 40];      // 30720 B
  const int tid = threadIdx.x;
  // 5408 blocks = 8 planes x 676. Plane p = b*2+h (one XCD per (b, ch-half));
  // rank = tile*4 + cgi: 4 consecutive blocks share one wgt tile (L2 reuse).
  int bid = blockIdx.x;
  int p = bid & 7;
  int rank = bid >> 3;
  const int b = p >> 1, h = p & 1;
  const int cgi = rank & 3;
  int tile = rank >> 2;
  const int ty = tile / 13, tx = tile % 13;
  const int x0 = tx * 16, y0 = ty * 16;
  const int c0 = (h * 4 + cgi) * 16;

  // zero both band buffers (scatter only ever writes the diagonal slots)
  for (int i = tid; i < 2560; i += 256)
    *(uint4*)&As2[i * 8] = uint4{0u, 0u, 0u, 0u};

  const int srow = tid >> 4, sm = tid & 15;
  const bool sval = (y0 + srow < H) && (x0 + sm < W);
  const ushort* wpix =
      wgt + ((size_t)b * 40000 + (size_t)(y0 + srow) * W + (x0 + sm)) * WST;
  // taps for the NEXT scatter live in (wa, w8)
  uint4 wa = uint4{0u, 0u, 0u, 0u};
  ushort w8 = 0;
  if (sval) {  // taps di=0 (byte offset 192*pix: 4B-aligned dword reads)
    const uint* wp32 = (const uint*)wpix;
    wa.x = wp32[0]; wa.y = wp32[1]; wa.z = wp32[2]; wa.w = wp32[3];
    w8 = wpix[8];
  }
  __syncthreads();  // zero-init visible before diagonal scatter

  // ---- stage Fs: 16 ch x 24 rows x 24 cols (halo 4), row stride 40 u16 ----
  const bool interior = (tx >= 1 && tx <= 11 && ty >= 1 && ty <= 11);
  if (interior) {
    const float* fb =
        fs + ((size_t)b * 128 + c0) * HW + (size_t)(y0 - 4) * W + (x0 - 4);
    for (int i = tid; i < 384; i += 256) {
      int c = i & 15, rf = i >> 4;
      const float4* src = (const float4*)(fb + (size_t)c * HW + (size_t)rf * W);
      float4 f0 = src[0], f1 = src[1], f2 = src[2];
      float4 f3 = src[3], f4 = src[4], f5 = src[5];
      ushort* dst = &Fs2[(rf * 16 + c) * 40];
      uint4 o;
      o.x = (uint)f2bf(f0.x) | ((uint)f2bf(f0.y) << 16);
      o.y = (uint)f2bf(f0.z) | ((uint)f2bf(f0.w) << 16);
      o.z = (uint)f2bf(f1.x) | ((uint)f2bf(f1.y) << 16);
      o.w = (uint)f2bf(f1.z) | ((uint)f2bf(f1.w) << 16);
      *(uint4*)&dst[0] = o;
      o.x = (uint)f2bf(f2.x) | ((uint)f2bf(f2.y) << 16);
      o.y = (uint)f2bf(f2.z) | ((uint)f2bf(f2.w) << 16);
      o.z = (uint)f2bf(f3.x) | ((uint)f2bf(f3.y) << 16);
      o.w = (uint)f2bf(f3.z) | ((uint)f2bf(f3.w) << 16);
      *(uint4*)&dst[8] = o;
      o.x = (uint)f2bf(f4.x) | ((uint)f2bf(f4.y) << 16);
      o.y = (uint)f2bf(f4.z) | ((uint)f2bf(f4.w) << 16);
      o.z = (uint)f2bf(f5.x) | ((uint)f2bf(f5.y) << 16);
      o.w = (uint)f2bf(f5.z) | ((uint)f2bf(f5.w) << 16);
      *(uint4*)&dst[16] = o;
      *(uint4*)&dst[24] = uint4{0u, 0u, 0u, 0u};  // pad k=24..31 (read by bf, A=0)
    }
  } else {
    const float* fb = fs + ((size_t)b * 128 + c0) * HW;
    for (int i = tid; i < 24 * 16 * 32; i += 256) {
      int k = i & 31;
      int c = (i >> 5) & 15;
      int rf = i >> 9;
      int gy = y0 - 4 + rf, gx = x0 - 4 + k;
      float v = 0.f;
      if (k < 24 && gy >= 0 && gy < H && gx >= 0 && gx < W)
        v = fb[(size_t)c * HW + (size_t)gy * W + gx];
      Fs2[(rf * 16 + c) * 40 + k] = f2bf(v);
    }
  }

  // scatter di=0 into buffer 0; preload taps di=1
  if (sval) {
    ushort* ap = &As2[(srow * 16 + sm) * 40 + sm];
    ap[0] = (ushort)wa.x; ap[1] = (ushort)(wa.x >> 16);
    ap[2] = (ushort)wa.y; ap[3] = (ushort)(wa.y >> 16);
    ap[4] = (ushort)wa.z; ap[5] = (ushort)(wa.z >> 16);
    ap[6] = (ushort)wa.w; ap[7] = (ushort)(wa.w >> 16);
    ap[8] = w8;
    const uint* wp32 = (const uint*)(wpix + 10);
    wa.x = wp32[0]; wa.y = wp32[1]; wa.z = wp32[2]; wa.w = wp32[3];
    w8 = wpix[18];
  }
  __syncthreads();

  const int lane = tid & 63, wave = tid >> 6;
  const int nl = lane & 15, kq = lane >> 4;
  f32x4 acc[4];
#pragma unroll
  for (int rr = 0; rr < 4; rr++) acc[rr] = f32x4{0.f, 0.f, 0.f, 0.f};

  for (int di = 0; di < 9; ++di) {
    const ushort* Ab = &As2[(di & 1) * 10240];
#pragma unroll
    for (int rr = 0; rr < 4; ++rr) {
      int row = wave * 4 + rr;
      bf16x8 af = *(const bf16x8*)&Ab[(row * 16 + nl) * 40 + kq * 8];
      bf16x8 bf = *(const bf16x8*)&Fs2[((row + di) * 16 + nl) * 40 + kq * 8];
      acc[rr] = __builtin_amdgcn_mfma_f32_16x16x32_bf16(af, bf, acc[rr], 0, 0, 0);
    }
    if (di < 8) {
      // scatter taps(di+1) into the other buffer (its last readers finished
      // before the previous barrier); then preload taps(di+2)
      if (sval) {
        ushort* ap = &As2[((di & 1) ^ 1) * 10240 + (srow * 16 + sm) * 40 + sm];
        ap[0] = (ushort)wa.x; ap[1] = (ushort)(wa.x >> 16);
        ap[2] = (ushort)wa.y; ap[3] = (ushort)(wa.y >> 16);
        ap[4] = (ushort)wa.z; ap[5] = (ushort)(wa.z >> 16);
        ap[6] = (ushort)wa.w; ap[7] = (ushort)(wa.w >> 16);
        ap[8] = w8;
        if (di < 7) {
          const uint* wp32 = (const uint*)(wpix + 10 * (di + 2));
          wa.x = wp32[0]; wa.y = wp32[1]; wa.z = wp32[2]; wa.w = wp32[3];
          w8 = wpix[10 * (di + 2) + 8];
        }
      }
    }
    __syncthreads();
  }

  // store: C row = kq*4+r -> x = x0+kq*4+r; col = nl -> channel
  const int xs = x0 + kq * 4;
  if (xs + 3 < W) {
    int c = c0 + nl;
#pragma unroll
    for (int rr = 0; rr < 4; ++rr) {
      int y = y0 + wave * 4 + rr;
      if (y < H) {
        *(float4*)&out[((size_t)b * 128 + c) * HW + (size_t)y * W + xs] =
            float4{acc[rr][0], acc[rr][1], acc[rr][2], acc[rr][3]};
      }
    }
  }
}

// ---------------- ag3 conv1x1 (32->1) + relu + 2-way softmax + blend ----------------
__global__ __launch_bounds__(256) void final_k(
    const float* __restrict__ a2, const float* __restrict__ w3,
    const float* __restrict__ b3, const float* __restrict__ alignb,
    const float* __restrict__ fcur, float* __restrict__ out) {
  int p = blockIdx.x * 256 + threadIdx.x;
  int bb = p / HW, pix = p % HW;
  const float* aS = a2 + (size_t)bb * 32 * HW + pix;
  const float* aC = a2 + (size_t)(bb + Bz) * 32 * HW + pix;
  float s0 = b3[0], s1 = b3[0];
#pragma unroll
  for (int c = 0; c < 32; c++) {
    float wv = w3[c];
    s0 += wv * aS[(size_t)c * HW];
    s1 += wv * aC[(size_t)c * HW];
  }
  s0 = fmaxf(s0, 0.f);
  s1 = fmaxf(s1, 0.f);
  float m = fmaxf(s0, s1);
  float e0 = expf(s0 - m), e1 = expf(s1 - m);
  float inv = 1.f / (e0 + e1);
  float p0 = e0 * inv, p1 = e1 * inv;
  const float* al = alignb + (size_t)bb * 128 * HW + pix;
  const float* fc = fcur + (size_t)bb * 128 * HW + pix;
  float* o = out + (size_t)bb * 128 * HW + pix;
#pragma unroll 4
  for (int c = 0; c < 128; c++)
    o[(size_t)c * HW] = p0 * al[(size_t)c * HW] + p1 * fc[(size_t)c * HW];
}

extern "C" void kernel_launch(void* const* d_in, const int* in_sizes, int n_in,
                              void* d_out, int out_size, void* d_ws, size_t ws_size,
                              hipStream_t stream) {
  const float* fsel = (const float*)d_in[0];
  const float* fcur = (const float*)d_in[1];
  const float* ec1_w = (const float*)d_in[2];
  const float* ec1_b = (const float*)d_in[3];
  const float* ec2_w = (const float*)d_in[4];
  const float* ec2_b = (const float*)d_in[5];
  const float* ag1_w = (const float*)d_in[6];
  const float* ag1_b = (const float*)d_in[7];
  const float* ag2_w = (const float*)d_in[8];
  const float* ag2_b = (const float*)d_in[9];
  const float* ag3_w = (const float*)d_in[10];
  const float* ag3_b = (const float*)d_in[11];

  char* ws = (char*)d_ws;
  size_t off = 4096;
  ushort* padbuf = (ushort*)(ws + off);
  size_t padbuf_bytes = (size_t)8 * PPLANE * 64 * 2;
  off += padbuf_bytes;
  ushort* epad = (ushort*)(ws + off);
  size_t epad_bytes = (size_t)8 * EPL * 64 * 2;
  off += epad_bytes + 4096;
  ushort* wgtb = (ushort*)(ws + off);
  off += (size_t)4 * 40000 * WST * 2 + 4096;
  float* alignb = (float*)(ws + off);
  off += (size_t)4 * 128 * HW * 4;
  ushort* wb1 = (ushort*)(ws + off);
  off += 9 * 64 * 64 * 2;
  ushort* wb2 = (ushort*)(ws + off);
  off += 9 * 32 * 64 * 2;
  float* a2 = (float*)epad;
  float* outp = (float*)d_out;

  dim3 blk(256);
  const int MTILES = (200 * PW + 255) / 256; // 163

  wxform_k<<<(9 * 64 * 64 + 255) / 256, blk, 0, stream>>>(ec2_w, wb1, 64);
  wxform_k<<<(9 * 32 * 64 + 255) / 256, blk, 0, stream>>>(ag2_w, wb2, 32);
  {
    int nz = (int)((padbuf_bytes + epad_bytes) / 16);
    zero_k<<<(nz + 255) / 256, blk, 0, stream>>>((uint4*)padbuf, nz);
  }
  conv1x1_nhwc_k<128><<<1250, blk, 0, stream>>>(fsel, fcur, ec1_w, ec1_b, padbuf);
  conv3x3_mfma_k<64, true><<<dim3(MTILES, 8), blk, 0, stream>>>(
      padbuf, wb1, ec2_b, nullptr, epad);
  corr_mfma_k<<<dim3(13, 100, 4), dim3(128), 0, stream>>>(epad, wgtb);
  align_mfma3_k<<<5408, blk, 0, stream>>>(wgtb, fsel, alignb);
  conv1x1_nhwc_k<128><<<1250, blk, 0, stream>>>(alignb, fcur, ag1_w, ag1_b, padbuf);
  conv3x3_mfma_k<32, false><<<dim3(MTILES, 8), blk, 0, stream>>>(
      padbuf, wb2, ag2_b, a2, nullptr);
  final_k<<<625, blk, 0, stream>>>(a2, ag3_w, ag3_b, alignb, fcur, outp);
}